// Round 12
// baseline (636.991 us; speedup 1.0000x reference)
//
#include <hip/hip_runtime.h>
#include <cmath>

#define CDIM 1024
#define NTOK 4096
#define NHEAD 16
#define HDIM 64
#define NEXP 8
#define HIDD 4096
#define MAXROWS 9216   // 72 tiles * 128

typedef short bf16x8 __attribute__((ext_vector_type(8)));
typedef short s16x4  __attribute__((ext_vector_type(4)));
typedef float f32x4  __attribute__((ext_vector_type(4)));

static __device__ __forceinline__ short f2bf(float f){
  unsigned u = __builtin_bit_cast(unsigned, f);
  u += 0x7fffu + ((u >> 16) & 1u);
  return (short)(u >> 16);
}
static __device__ __forceinline__ float bf2f(short s){
  unsigned u = ((unsigned)(unsigned short)s) << 16;
  return __builtin_bit_cast(float, u);
}
// tanh-form GELU (|diff vs exact erf-GELU| <= ~3e-3, well within threshold)
static __device__ __forceinline__ float gelu_t(float x){
  const float y = 0.7978845608f*(x + 0.044715f*x*x*x);
  const float e = __expf(2.f*y);
  return 0.5f*x*(1.f + (e-1.f)/(e+1.f));
}

// swizzle for 64-byte rows (32 bf16), 16B chunks ch=0..3 (measured 0-conflict)
static __device__ __forceinline__ int swz64(int r, int ch){
  return r*64 + (((ch ^ (r>>1)) & 3) << 4);
}
// swizzle for 128-byte rows (64 bf16), 16B chunks ch=0..7
static __device__ __forceinline__ int swz128(int r, int ch){
  return r*128 + (((ch ^ r) & 7) << 4);
}

// async 16B global->LDS; lds base must be wave-uniform, HW adds lane*16
static __device__ __forceinline__ void gl16(const short* g, short* l){
  __builtin_amdgcn_global_load_lds(
      (const __attribute__((address_space(1))) void*)g,
      (__attribute__((address_space(3))) void*)l, 16, 0, 0);
}

// ---------------- transpose + fp32->bf16 cast:  out[c][r] = in[r][c] ----------------
__global__ void k_transpose_cast(const float* __restrict__ in, short* __restrict__ out,
                                 int R, int Cc){
  __shared__ float tile[64][65];
  const int z = blockIdx.z;
  const float* src = in + (long long)z*R*Cc;
  short* dst = out + (long long)z*R*Cc;
  const int r0 = blockIdx.y*64, c0 = blockIdx.x*64;
  const int t = threadIdx.x;
  #pragma unroll
  for (int it=0; it<4; ++it){
    const int item = t + it*256;
    const int r = item>>4, c4 = item&15;
    const float4 v = *(const float4*)(src + (long long)(r0+r)*Cc + c0 + c4*4);
    tile[r][c4*4+0]=v.x; tile[r][c4*4+1]=v.y; tile[r][c4*4+2]=v.z; tile[r][c4*4+3]=v.w;
  }
  __syncthreads();
  #pragma unroll
  for (int it=0; it<2; ++it){
    const int item = t + it*256;
    const int rr8 = item & 7, cc = item >> 3;
    bf16x8 o;
    #pragma unroll
    for (int i=0;i<8;i++) o[i] = f2bf(tile[rr8*8+i][cc]);
    *(bf16x8*)(dst + (long long)(c0+cc)*R + r0 + rr8*8) = o;
  }
}

// ---------------- LayerNorm 1 -> bf16 ----------------
__global__ void k_ln1(const float* __restrict__ x, const float* __restrict__ g,
                      const float* __restrict__ b, short* __restrict__ out){
  const int row = blockIdx.x;
  const int t = threadIdx.x;
  const float4 v = ((const float4*)(x + (long long)row*CDIM))[t];
  float s  = v.x+v.y+v.z+v.w;
  float s2 = v.x*v.x+v.y*v.y+v.z*v.z+v.w*v.w;
  #pragma unroll
  for (int mm=1; mm<64; mm<<=1){ s += __shfl_xor(s,mm); s2 += __shfl_xor(s2,mm); }
  __shared__ float ps[4], ps2[4];
  const int w = t>>6, l = t&63;
  if (l==0){ ps[w]=s; ps2[w]=s2; }
  __syncthreads();
  s  = ps[0]+ps[1]+ps[2]+ps[3];
  s2 = ps2[0]+ps2[1]+ps2[2]+ps2[3];
  const float mu = s*(1.f/CDIM);
  const float rstd = rsqrtf(s2*(1.f/CDIM) - mu*mu + 1e-5f);
  const float4 gg = ((const float4*)g)[t];
  const float4 bb = ((const float4*)b)[t];
  s16x4 o;
  o[0]=f2bf((v.x-mu)*rstd*gg.x+bb.x); o[1]=f2bf((v.y-mu)*rstd*gg.y+bb.y);
  o[2]=f2bf((v.z-mu)*rstd*gg.z+bb.z); o[3]=f2bf((v.w-mu)*rstd*gg.w+bb.w);
  *(s16x4*)(out + (long long)row*CDIM + t*4) = o;
}

// ---------------- LayerNorm 2 + router (fp32 logits) ----------------
__global__ void k_ln2_router(const float* __restrict__ x1, const float* __restrict__ g,
                             const float* __restrict__ b, const float* __restrict__ Wr,
                             short* __restrict__ h2, int* __restrict__ tidx,
                             float* __restrict__ tw, int* __restrict__ counts){
  const int row = blockIdx.x;
  const int t = threadIdx.x;
  const float4 v = ((const float4*)(x1 + (long long)row*CDIM))[t];
  float s  = v.x+v.y+v.z+v.w;
  float s2 = v.x*v.x+v.y*v.y+v.z*v.z+v.w*v.w;
  #pragma unroll
  for (int mm=1; mm<64; mm<<=1){ s += __shfl_xor(s,mm); s2 += __shfl_xor(s2,mm); }
  __shared__ float ps[4], ps2[4];
  const int w = t>>6, l = t&63;
  if (l==0){ ps[w]=s; ps2[w]=s2; }
  __syncthreads();
  s  = ps[0]+ps[1]+ps[2]+ps[3];
  s2 = ps2[0]+ps2[1]+ps2[2]+ps2[3];
  const float mu = s*(1.f/CDIM);
  const float rstd = rsqrtf(s2*(1.f/CDIM) - mu*mu + 1e-5f);
  const float4 gg = ((const float4*)g)[t];
  const float4 bb = ((const float4*)b)[t];
  const float y0=(v.x-mu)*rstd*gg.x+bb.x, y1=(v.y-mu)*rstd*gg.y+bb.y;
  const float y2=(v.z-mu)*rstd*gg.z+bb.z, y3=(v.w-mu)*rstd*gg.w+bb.w;
  s16x4 o; o[0]=f2bf(y0); o[1]=f2bf(y1); o[2]=f2bf(y2); o[3]=f2bf(y3);
  *(s16x4*)(h2 + (long long)row*CDIM + t*4) = o;

  float acc[8];
  const float* wr0 = Wr + (long long)(t*4)*NEXP;
  #pragma unroll
  for (int e=0;e<8;e++) acc[e] = y0*wr0[e] + y1*wr0[8+e] + y2*wr0[16+e] + y3*wr0[24+e];
  #pragma unroll
  for (int mm=1; mm<64; mm<<=1){
    #pragma unroll
    for (int e=0;e<8;e++) acc[e] += __shfl_xor(acc[e], mm);
  }
  __shared__ float pl[4][8];
  if (l==0){
    #pragma unroll
    for (int e=0;e<8;e++) pl[w][e]=acc[e];
  }
  __syncthreads();
  if (t==0){
    float lg[8];
    #pragma unroll
    for (int e=0;e<8;e++) lg[e] = pl[0][e]+pl[1][e]+pl[2][e]+pl[3][e];
    float mx = lg[0];
    #pragma unroll
    for (int e=1;e<8;e++) mx = fmaxf(mx, lg[e]);
    float pr[8]; float sum = 0.f;
    #pragma unroll
    for (int e=0;e<8;e++){ pr[e]=expf(lg[e]-mx); sum += pr[e]; }
    int i0 = 0;
    #pragma unroll
    for (int e=1;e<8;e++) if (pr[e] > pr[i0]) i0 = e;
    int i1 = (i0==0) ? 1 : 0;
    #pragma unroll
    for (int e=0;e<8;e++) if (e!=i0 && pr[e] > pr[i1]) i1 = e;
    const float p0 = pr[i0]/sum, p1 = pr[i1]/sum;
    const float dn = p0 + p1 + 1e-9f;
    tidx[row*2]=i0; tidx[row*2+1]=i1;
    tw[row*2]=p0/dn; tw[row*2+1]=p1/dn;
    atomicAdd(&counts[i0],1); atomicAdd(&counts[i1],1);
  }
}

// ---------------- routing setup (tiny; rowmap pre-initialized by memset 0xFF) -------
__global__ void k_route_setup(const int* __restrict__ counts, int* __restrict__ offs,
                              int* __restrict__ cursors, float* __restrict__ util){
  if (threadIdx.x == 0){
    int o = 0;
    for (int e=0;e<8;e++){
      offs[e] = o; cursors[e] = o;
      o += (counts[e] + 127) & ~127;
    }
    offs[8] = o;
    for (int e=0;e<8;e++) util[e] = (float)counts[e] / 8192.0f;
  }
}

// ---------------- scatter tokens to expert segments ----------------
__global__ void k_scatter(const int* __restrict__ tidx, const float* __restrict__ tw,
                          int* __restrict__ cursors, int* __restrict__ rowmap,
                          float* __restrict__ roww, int* __restrict__ posmap){
  const int i = blockIdx.x*blockDim.x + threadIdx.x;
  if (i >= 2*NTOK) return;
  const int e = tidx[i];
  const int pos = atomicAdd(&cursors[e], 1);
  rowmap[pos] = i >> 1;
  roww[pos]   = tw[i];
  posmap[i]   = pos;
}

// ---------------- GEMM 128x128 (proven): 512 thr, 2-buf, vmcnt(0) ----------
// EPI 0: +bias -> bf16 (QKV) | EPI 1: +bias +resid -> f32 (proj)
// EPI 3: per-expert bias -> bf16 (MoE down)
template<int EPI>
__launch_bounds__(512, 4)
__global__ void k_gemm(const short* __restrict__ A, const short* __restrict__ Bt,
                       const float* __restrict__ bias, const float* __restrict__ resid,
                       void* __restrict__ Cout, int N, int K,
                       const int* __restrict__ offs, long long expStrideB){
  // bijective XCD swizzle (m204)
  int wg = blockIdx.x;
  const int nwg = gridDim.x;
  {
    const int q = nwg >> 3, r8 = nwg & 7;
    const int xcd = wg & 7, pos = wg >> 3;
    wg = (xcd < r8 ? xcd*(q+1) : r8*(q+1) + (xcd - r8)*q) + pos;
  }
  const int gridN = N >> 7;
  const int gridM = nwg / gridN;
  const int mtile = wg % gridM, ntile = wg / gridM;
  const int mbase = mtile*128;
  const int nbase = ntile*128;
  int e = 0;
  if constexpr (EPI == 3){
    if (mbase >= offs[8]) return;
    while (e < 7 && mbase >= offs[e+1]) e++;
    Bt += (long long)e * expStrideB;
  }
  __shared__ short Asm[2][4096];
  __shared__ short Bsm[2][4096];
  const int tid = threadIdx.x;
  const int w = tid >> 6, l = tid & 63;
  const int wr = w >> 1, wc = w & 1;       // 4M x 2N wave grid
  const int l15 = l & 15, l4 = l >> 4;

  const short* aSrc; const short* bSrc;
  {
    const int r = tid >> 2, ch = tid & 3;
    const int sch = (ch ^ (r >> 1)) & 3;   // source chunk (involution of swz64)
    aSrc = A + (long long)(mbase + r)*K + sch*8;
    bSrc = Bt + (long long)(nbase + r)*K + sch*8;
  }
  const int dOff = w*512;                  // wave-uniform shorts offset

  f32x4 acc[2][4];
  const f32x4 z4 = {0.f,0.f,0.f,0.f};
  #pragma unroll
  for (int i=0;i<2;i++){
    #pragma unroll
    for (int jn=0;jn<4;jn++) acc[i][jn] = z4;
  }

  auto stage = [&](int buf, int kt){
    gl16(aSrc + kt, &Asm[buf][dOff]);
    gl16(bSrc + kt, &Bsm[buf][dOff]);
  };
  auto compute = [&](int buf){
    bf16x8 af[2], bfr[4];
    #pragma unroll
    for (int i=0;i<2;i++)
      af[i]  = *(const bf16x8*)((char*)Asm[buf] + swz64(wr*32 + i*16 + l15, l4));
    #pragma unroll
    for (int jn=0;jn<4;jn++)
      bfr[jn] = *(const bf16x8*)((char*)Bsm[buf] + swz64(wc*64 + jn*16 + l15, l4));
    #pragma unroll
    for (int i=0;i<2;i++){
      #pragma unroll
      for (int jn=0;jn<4;jn++)
        acc[i][jn] = __builtin_amdgcn_mfma_f32_16x16x32_bf16(af[i], bfr[jn], acc[i][jn], 0,0,0);
    }
  };

  stage(0, 0);
  asm volatile("s_waitcnt vmcnt(0)" ::: "memory");
  __builtin_amdgcn_s_barrier();

  int cur = 0;
  for (int kt = 32; kt < K; kt += 32){
    stage(cur ^ 1, kt);
    compute(cur);
    asm volatile("s_waitcnt vmcnt(0)" ::: "memory");
    __builtin_amdgcn_s_barrier();
    cur ^= 1;
  }
  compute(cur);

  #pragma unroll
  for (int i=0;i<2;i++){
    const int row0 = mbase + wr*32 + i*16 + l4*4;
    #pragma unroll
    for (int jn=0;jn<4;jn++){
      const int col = nbase + wc*64 + jn*16 + l15;
      const float bi = bias[(EPI==3 ? e*N : 0) + col];
      #pragma unroll
      for (int j=0;j<4;j++){
        const long long idx = (long long)(row0 + j)*N + col;
        float v = acc[i][jn][j] + bi;
        if constexpr (EPI == 0){
          ((short*)Cout)[idx] = f2bf(v);
        } else if constexpr (EPI == 1){
          ((float*)Cout)[idx] = v + resid[idx];
        } else {
          ((short*)Cout)[idx] = f2bf(v);
        }
      }
    }
  }
}

// ---------------- MoE-up GEMM: 128x256 tile, wave-tile 64x64 (512 B LDS/MFMA) -------
// 512 thr = 8 waves (2M x 4N), acc[4][4]; gathered A rows; GELU(tanh) -> bf16.
__launch_bounds__(512, 4)
__global__ void k_gemm_up(const short* __restrict__ A, const short* __restrict__ Bt,
                          const float* __restrict__ bias, short* __restrict__ Cout,
                          int N, int K, const int* __restrict__ rowmap,
                          const int* __restrict__ offs, long long expStrideB,
                          const short* __restrict__ zrow){
  int wg = blockIdx.x;
  const int nwg = gridDim.x;
  {
    const int q = nwg >> 3, r8 = nwg & 7;
    const int xcd = wg & 7, pos = wg >> 3;
    wg = (xcd < r8 ? xcd*(q+1) : r8*(q+1) + (xcd - r8)*q) + pos;
  }
  const int gridN = N >> 8;
  const int gridM = nwg / gridN;
  const int mtile = wg % gridM, ntile = wg / gridM;
  const int mbase = mtile*128;
  const int nbase = ntile*256;
  if (mbase >= offs[8]) return;
  int e = 0;
  while (e < 7 && mbase >= offs[e+1]) e++;
  Bt += (long long)e * expStrideB;

  __shared__ short Asm[2][4096];    // 128 x 32
  __shared__ short Bsm[2][8192];    // 256 x 32
  const int tid = threadIdx.x;
  const int w = tid >> 6, l = tid & 63;
  const int wr = w >> 2, wc = w & 3;       // 2M x 4N wave grid
  const int l15 = l & 15, l4 = l >> 4;

  const short* aSrc; const short* bSrc[2];
  {
    const int r = tid >> 2, ch = tid & 3;
    const int sch = (ch ^ (r >> 1)) & 3;
    const int grow = rowmap[mbase + r];
    aSrc = (grow >= 0) ? (A + (long long)grow*K + sch*8) : (zrow + sch*8);
  }
  #pragma unroll
  for (int inst=0; inst<2; ++inst){
    const int g = inst*512 + tid;          // B chunk 0..1023
    const int r = g >> 2, ch = g & 3;
    const int sch = (ch ^ (r >> 1)) & 3;
    bSrc[inst] = Bt + (long long)(nbase + r)*K + sch*8;
  }
  const int aOff = w*512;
  const int bOff0 = w*512, bOff1 = 4096 + w*512;

  f32x4 acc[4][4];
  const f32x4 z4 = {0.f,0.f,0.f,0.f};
  #pragma unroll
  for (int i=0;i<4;i++){
    #pragma unroll
    for (int jn=0;jn<4;jn++) acc[i][jn] = z4;
  }

  auto stage = [&](int buf, int kt){
    gl16(aSrc + kt, &Asm[buf][aOff]);
    gl16(bSrc[0] + kt, &Bsm[buf][bOff0]);
    gl16(bSrc[1] + kt, &Bsm[buf][bOff1]);
  };
  auto compute = [&](int buf){
    bf16x8 af[4], bfr[4];
    #pragma unroll
    for (int i=0;i<4;i++)
      af[i]  = *(const bf16x8*)((char*)Asm[buf] + swz64(wr*64 + i*16 + l15, l4));
    #pragma unroll
    for (int jn=0;jn<4;jn++)
      bfr[jn] = *(const bf16x8*)((char*)Bsm[buf] + swz64(wc*64 + jn*16 + l15, l4));
    #pragma unroll
    for (int i=0;i<4;i++){
      #pragma unroll
      for (int jn=0;jn<4;jn++)
        acc[i][jn] = __builtin_amdgcn_mfma_f32_16x16x32_bf16(af[i], bfr[jn], acc[i][jn], 0,0,0);
    }
  };

  stage(0, 0);
  asm volatile("s_waitcnt vmcnt(0)" ::: "memory");
  __builtin_amdgcn_s_barrier();

  int cur = 0;
  for (int kt = 32; kt < K; kt += 32){
    stage(cur ^ 1, kt);
    compute(cur);
    asm volatile("s_waitcnt vmcnt(0)" ::: "memory");
    __builtin_amdgcn_s_barrier();
    cur ^= 1;
  }
  compute(cur);

  #pragma unroll
  for (int i=0;i<4;i++){
    const int row0 = mbase + wr*64 + i*16 + l4*4;
    #pragma unroll
    for (int jn=0;jn<4;jn++){
      const int col = nbase + wc*64 + jn*16 + l15;
      const float bi = bias[e*N + col];
      #pragma unroll
      for (int j=0;j<4;j++){
        const long long idx = (long long)(row0 + j)*N + col;
        Cout[idx] = f2bf(gelu_t(acc[i][jn][j] + bi));
      }
    }
  }
}

// ---------------- flash attention (causal), 128 q rows / block, 8 waves ----------------
__launch_bounds__(512)
__global__ void k_attn(const short* __restrict__ qkv, short* __restrict__ y){
  const int qp = blockIdx.x;       // q pair (128 rows)
  const int bh = blockIdx.y;
  const int bb = bh >> 4;
  const int h  = bh & 15;
  const int tid = threadIdx.x;
  const int w = tid >> 6, l = tid & 63;
  const int half = w >> 2, wq = w & 3;
  const int l15 = l & 15, l4 = l >> 4;

  __shared__ short Ksm[64*64];
  __shared__ short Vtsm[64*64];
  __shared__ short Psm[8*16*64];

  const long long rs = 3*CDIM;
  const int qrow0 = bb*1024 + qp*128;
  const int myQt = (qp << 1) + half;
  const int qtHigh = (qp << 1) + 1;

  bf16x8 aq[2];
  {
    const int qr = qrow0 + half*64 + wq*16 + l15;
    const short* qp2 = qkv + (long long)qr*rs + h*HDIM;
    aq[0] = *(const bf16x8*)(qp2 + l4*8);
    aq[1] = *(const bf16x8*)(qp2 + 32 + l4*8);
  }

  const f32x4 z4 = {0.f,0.f,0.f,0.f};
  f32x4 O[4];
  #pragma unroll
  for (int cf=0;cf<4;cf++) O[cf] = z4;
  float mrow[4], lrow[4];
  #pragma unroll
  for (int j=0;j<4;j++){ mrow[j] = -1e30f; lrow[j] = 0.f; }

  for (int kvb = 0; kvb <= qtHigh; ++kvb){
    const int kvrow0 = bb*1024 + kvb*64;
    {
      const int r = tid >> 3, c = tid & 7;
      const short* kp = qkv + (long long)(kvrow0 + r)*rs + CDIM + h*HDIM + c*8;
      *(bf16x8*)((char*)Ksm + swz128(r, c)) = *(const bf16x8*)kp;
      const short* vp = qkv + (long long)(kvrow0 + r)*rs + 2*CDIM + h*HDIM + c*8;
      bf16x8 vv = *(const bf16x8*)vp;
      const int off2 = 2*r;
      const int g0 = off2 >> 4, b0 = off2 & 15;
      #pragma unroll
      for (int i=0;i<8;i++){
        const int d = c*8 + i;
        *(short*)((char*)Vtsm + d*128 + (((g0 ^ d) & 7) << 4) + b0) = vv[i];
      }
    }
    __syncthreads();

    if (kvb <= myQt){
      f32x4 S[4];
      #pragma unroll
      for (int cf=0;cf<4;cf++) S[cf] = z4;
      #pragma unroll
      for (int cf=0;cf<4;cf++){
        #pragma unroll
        for (int kf=0;kf<2;kf++){
          bf16x8 bk = *(const bf16x8*)((char*)Ksm + swz128(cf*16 + l15, kf*4 + l4));
          S[cf] = __builtin_amdgcn_mfma_f32_16x16x32_bf16(aq[kf], bk, S[cf], 0,0,0);
        }
      }

      const bool diag = (kvb == myQt);
      #pragma unroll
      for (int cf=0;cf<4;cf++){
        #pragma unroll
        for (int j=0;j<4;j++){
          float s = S[cf][j] * 0.125f;
          if (diag && (cf*16 + l15 > wq*16 + l4*4 + j)) s = -1e30f;
          S[cf][j] = s;
        }
      }

      float alpha[4];
      #pragma unroll
      for (int j=0;j<4;j++){
        float mx = fmaxf(fmaxf(S[0][j],S[1][j]), fmaxf(S[2][j],S[3][j]));
        #pragma unroll
        for (int mm=1; mm<16; mm<<=1) mx = fmaxf(mx, __shfl_xor(mx, mm));
        const float mnew = fmaxf(mrow[j], mx);
        const float al = expf(mrow[j] - mnew);
        float psum = 0.f;
        #pragma unroll
        for (int cf=0;cf<4;cf++){ float pp = expf(S[cf][j]-mnew); S[cf][j]=pp; psum += pp; }
        #pragma unroll
        for (int mm=1; mm<16; mm<<=1) psum += __shfl_xor(psum, mm);
        lrow[j] = lrow[j]*al + psum;
        mrow[j] = mnew; alpha[j] = al;
      }
      #pragma unroll
      for (int cf=0;cf<4;cf++){
        #pragma unroll
        for (int j=0;j<4;j++) O[cf][j] *= alpha[j];
      }

      char* pw = (char*)Psm + w*2048;
      #pragma unroll
      for (int cf=0;cf<4;cf++){
        #pragma unroll
        for (int j=0;j<4;j++){
          const int r = l4*4 + j;
          const int cb = (cf*16 + l15)*2;
          *(short*)(pw + r*128 + ((((cb>>4) ^ r) & 7)<<4) + (cb & 15)) = f2bf(S[cf][j]);
        }
      }
      bf16x8 pa[2];
      pa[0] = *(const bf16x8*)(pw + swz128(l15, l4));
      pa[1] = *(const bf16x8*)(pw + swz128(l15, 4 + l4));
      #pragma unroll
      for (int cf=0;cf<4;cf++){
        #pragma unroll
        for (int kf=0;kf<2;kf++){
          bf16x8 bv = *(const bf16x8*)((char*)Vtsm + swz128(cf*16 + l15, kf*4 + l4));
          O[cf] = __builtin_amdgcn_mfma_f32_16x16x32_bf16(pa[kf], bv, O[cf], 0,0,0);
        }
      }
    }
    __syncthreads();
  }

  const int yr0 = qrow0 + half*64 + wq*16;
  #pragma unroll
  for (int cf=0;cf<4;cf++){
    #pragma unroll
    for (int j=0;j<4;j++){
      const int r = l4*4 + j;
      y[(long long)(yr0 + r)*CDIM + h*HDIM + cf*16 + l15] = f2bf(O[cf][j] / lrow[j]);
    }
  }
}

// ---------------- final combine: out = x1 + w0*eo[p0] + w1*eo[p1] (eo bf16) ---------
__global__ void k_combine(const float* __restrict__ x1, const short* __restrict__ eo,
                          const int* __restrict__ posmap, const float* __restrict__ roww,
                          float* __restrict__ out){
  const int row = blockIdx.x;
  const int t = threadIdx.x;
  const int p0 = posmap[row*2], p1 = posmap[row*2+1];
  const float w0 = roww[p0], w1 = roww[p1];
  const float4 a  = ((const float4*)(x1 + (long long)row*CDIM))[t];
  const s16x4 e0 = *(const s16x4*)(eo + (long long)p0*CDIM + t*4);
  const s16x4 e1 = *(const s16x4*)(eo + (long long)p1*CDIM + t*4);
  float4 r;
  r.x = a.x + w0*bf2f(e0[0]) + w1*bf2f(e1[0]);
  r.y = a.y + w0*bf2f(e0[1]) + w1*bf2f(e1[1]);
  r.z = a.z + w0*bf2f(e0[2]) + w1*bf2f(e1[2]);
  r.w = a.w + w0*bf2f(e0[3]) + w1*bf2f(e1[3]);
  ((float4*)(out + (long long)row*CDIM))[t] = r;
}

extern "C" void kernel_launch(void* const* d_in, const int* in_sizes, int n_in,
                              void* d_out, int out_size, void* d_ws, size_t ws_size,
                              hipStream_t stream){
  const float* x     = (const float*)d_in[0];
  const float* ln1_g = (const float*)d_in[1];
  const float* ln1_b = (const float*)d_in[2];
  const float* W_qkv = (const float*)d_in[3];
  const float* b_qkv = (const float*)d_in[4];
  const float* W_proj= (const float*)d_in[5];
  const float* b_proj= (const float*)d_in[6];
  const float* ln2_g = (const float*)d_in[7];
  const float* ln2_b = (const float*)d_in[8];
  const float* W_r   = (const float*)d_in[9];
  const float* W1    = (const float*)d_in[10];
  const float* b1    = (const float*)d_in[11];
  const float* W2    = (const float*)d_in[12];
  const float* b2    = (const float*)d_in[13];
  float* out = (float*)d_out;
  float* util = out + (long long)NTOK*CDIM;

  char* p = (char*)d_ws;
  auto alloc = [&](size_t bytes)->char*{
    char* r = p; p += (bytes + 255) & ~(size_t)255; return r;
  };
  // persistent region
  short* Wt1   = (short*)alloc((size_t)NEXP*HIDD*CDIM*2);
  short* Wt2   = (short*)alloc((size_t)NEXP*CDIM*HIDD*2);
  float* x1    = (float*)alloc((size_t)NTOK*CDIM*4);
  short* h2    = (short*)alloc((size_t)NTOK*CDIM*2);
  short* hid   = (short*)alloc((size_t)MAXROWS*HIDD*2);
  int*   tidx  = (int*)alloc(2*NTOK*4);
  float* tw    = (float*)alloc(2*NTOK*4);
  int*   counts= (int*)alloc(256);
  int*   offs  = (int*)alloc(256);
  int*   curs  = (int*)alloc(256);
  int*   rowmap= (int*)alloc(MAXROWS*4);
  float* roww  = (float*)alloc(MAXROWS*4);
  int*   posmap= (int*)alloc(2*NTOK*4);
  short* zrow  = (short*)alloc(8192);
  // transient region (dead after proj GEMM) -- eo aliases it afterwards
  char* transStart = p;
  short* WtQ = (short*)alloc((size_t)3*CDIM*CDIM*2);
  short* WtP = (short*)alloc((size_t)CDIM*CDIM*2);
  short* h   = (short*)alloc((size_t)NTOK*CDIM*2);
  short* qkv = (short*)alloc((size_t)NTOK*3*CDIM*2);
  short* y   = (short*)alloc((size_t)NTOK*CDIM*2);
  short* eo  = (short*)transStart;  // MAXROWS*CDIM*2 = 18.9MB <= transient

  (void)hipMemsetAsync(counts, 0, 32, stream);
  (void)hipMemsetAsync(zrow, 0, 8192, stream);
  (void)hipMemsetAsync(rowmap, 0xFF, MAXROWS*4, stream);

  k_transpose_cast<<<dim3(3*CDIM/64, CDIM/64, 1), 256, 0, stream>>>(W_qkv, WtQ, CDIM, 3*CDIM);
  k_transpose_cast<<<dim3(CDIM/64, CDIM/64, 1),   256, 0, stream>>>(W_proj, WtP, CDIM, CDIM);
  k_transpose_cast<<<dim3(HIDD/64, CDIM/64, NEXP),256, 0, stream>>>(W1, Wt1, CDIM, HIDD);
  k_transpose_cast<<<dim3(CDIM/64, HIDD/64, NEXP),256, 0, stream>>>(W2, Wt2, HIDD, CDIM);

  k_ln1<<<NTOK, 256, 0, stream>>>(x, ln1_g, ln1_b, h);

  k_gemm<0><<<dim3((NTOK/128)*(3*CDIM/128)), 512, 0, stream>>>(
      h, WtQ, b_qkv, nullptr, qkv, 3*CDIM, CDIM, nullptr, 0);

  k_attn<<<dim3(1024/128, 4*NHEAD), 512, 0, stream>>>(qkv, y);

  k_gemm<1><<<dim3((NTOK/128)*(CDIM/128)), 512, 0, stream>>>(
      y, WtP, b_proj, x, x1, CDIM, CDIM, nullptr, 0);

  k_ln2_router<<<NTOK, 256, 0, stream>>>(x1, ln2_g, ln2_b, W_r, h2, tidx, tw, counts);
  k_route_setup<<<1, 64, 0, stream>>>(counts, offs, curs, util);
  k_scatter<<<(2*NTOK)/256, 256, 0, stream>>>(tidx, tw, curs, rowmap, roww, posmap);

  k_gemm_up<<<dim3((MAXROWS/128)*(HIDD/256)), 512, 0, stream>>>(
      h2, Wt1, b1, hid, HIDD, CDIM, rowmap, offs, (long long)HIDD*CDIM, zrow);
  k_gemm<3><<<dim3((MAXROWS/128)*(CDIM/128)), 512, 0, stream>>>(
      hid, Wt2, b2, nullptr, eo, CDIM, HIDD, offs, (long long)CDIM*HIDD);

  k_combine<<<NTOK, 256, 0, stream>>>(x1, eo, posmap, roww, out);
}

// Round 13
// 627.061 us; speedup vs baseline: 1.0158x; 1.0158x over previous
//
#include <hip/hip_runtime.h>
#include <cmath>

#define CDIM 1024
#define NTOK 4096
#define NHEAD 16
#define HDIM 64
#define NEXP 8
#define HIDD 4096
#define MAXROWS 9216   // 72 tiles * 128

typedef short bf16x8 __attribute__((ext_vector_type(8)));
typedef short s16x4  __attribute__((ext_vector_type(4)));
typedef float f32x4  __attribute__((ext_vector_type(4)));

static __device__ __forceinline__ short f2bf(float f){
  unsigned u = __builtin_bit_cast(unsigned, f);
  u += 0x7fffu + ((u >> 16) & 1u);
  return (short)(u >> 16);
}
static __device__ __forceinline__ float bf2f(short s){
  unsigned u = ((unsigned)(unsigned short)s) << 16;
  return __builtin_bit_cast(float, u);
}
// tanh-form GELU (|diff vs exact erf-GELU| <= ~3e-3, well within threshold)
static __device__ __forceinline__ float gelu_t(float x){
  const float y = 0.7978845608f*(x + 0.044715f*x*x*x);
  const float e = __expf(2.f*y);
  return 0.5f*x*(1.f + (e-1.f)/(e+1.f));
}

// swizzle for 64-byte rows (32 bf16), 16B chunks ch=0..3 (measured 0-conflict)
static __device__ __forceinline__ int swz64(int r, int ch){
  return r*64 + (((ch ^ (r>>1)) & 3) << 4);
}
// swizzle for 128-byte rows (64 bf16), 16B chunks ch=0..7
static __device__ __forceinline__ int swz128(int r, int ch){
  return r*128 + (((ch ^ r) & 7) << 4);
}

// async 16B global->LDS; lds base must be wave-uniform, HW adds lane*16
static __device__ __forceinline__ void gl16(const short* g, short* l){
  __builtin_amdgcn_global_load_lds(
      (const __attribute__((address_space(1))) void*)g,
      (__attribute__((address_space(3))) void*)l, 16, 0, 0);
}

// ---------------- transpose + fp32->bf16 cast:  out[c][r] = in[r][c] ----------------
__global__ void k_transpose_cast(const float* __restrict__ in, short* __restrict__ out,
                                 int R, int Cc){
  __shared__ float tile[64][65];
  const int z = blockIdx.z;
  const float* src = in + (long long)z*R*Cc;
  short* dst = out + (long long)z*R*Cc;
  const int r0 = blockIdx.y*64, c0 = blockIdx.x*64;
  const int t = threadIdx.x;
  #pragma unroll
  for (int it=0; it<4; ++it){
    const int item = t + it*256;
    const int r = item>>4, c4 = item&15;
    const float4 v = *(const float4*)(src + (long long)(r0+r)*Cc + c0 + c4*4);
    tile[r][c4*4+0]=v.x; tile[r][c4*4+1]=v.y; tile[r][c4*4+2]=v.z; tile[r][c4*4+3]=v.w;
  }
  __syncthreads();
  #pragma unroll
  for (int it=0; it<2; ++it){
    const int item = t + it*256;
    const int rr8 = item & 7, cc = item >> 3;
    bf16x8 o;
    #pragma unroll
    for (int i=0;i<8;i++) o[i] = f2bf(tile[rr8*8+i][cc]);
    *(bf16x8*)(dst + (long long)(c0+cc)*R + r0 + rr8*8) = o;
  }
}

// ---------------- LayerNorm 1 -> bf16 ----------------
__global__ void k_ln1(const float* __restrict__ x, const float* __restrict__ g,
                      const float* __restrict__ b, short* __restrict__ out){
  const int row = blockIdx.x;
  const int t = threadIdx.x;
  const float4 v = ((const float4*)(x + (long long)row*CDIM))[t];
  float s  = v.x+v.y+v.z+v.w;
  float s2 = v.x*v.x+v.y*v.y+v.z*v.z+v.w*v.w;
  #pragma unroll
  for (int mm=1; mm<64; mm<<=1){ s += __shfl_xor(s,mm); s2 += __shfl_xor(s2,mm); }
  __shared__ float ps[4], ps2[4];
  const int w = t>>6, l = t&63;
  if (l==0){ ps[w]=s; ps2[w]=s2; }
  __syncthreads();
  s  = ps[0]+ps[1]+ps[2]+ps[3];
  s2 = ps2[0]+ps2[1]+ps2[2]+ps2[3];
  const float mu = s*(1.f/CDIM);
  const float rstd = rsqrtf(s2*(1.f/CDIM) - mu*mu + 1e-5f);
  const float4 gg = ((const float4*)g)[t];
  const float4 bb = ((const float4*)b)[t];
  s16x4 o;
  o[0]=f2bf((v.x-mu)*rstd*gg.x+bb.x); o[1]=f2bf((v.y-mu)*rstd*gg.y+bb.y);
  o[2]=f2bf((v.z-mu)*rstd*gg.z+bb.z); o[3]=f2bf((v.w-mu)*rstd*gg.w+bb.w);
  *(s16x4*)(out + (long long)row*CDIM + t*4) = o;
}

// ---------------- LayerNorm 2 + router (fp32 logits) ----------------
__global__ void k_ln2_router(const float* __restrict__ x1, const float* __restrict__ g,
                             const float* __restrict__ b, const float* __restrict__ Wr,
                             short* __restrict__ h2, int* __restrict__ tidx,
                             float* __restrict__ tw, int* __restrict__ counts){
  const int row = blockIdx.x;
  const int t = threadIdx.x;
  const float4 v = ((const float4*)(x1 + (long long)row*CDIM))[t];
  float s  = v.x+v.y+v.z+v.w;
  float s2 = v.x*v.x+v.y*v.y+v.z*v.z+v.w*v.w;
  #pragma unroll
  for (int mm=1; mm<64; mm<<=1){ s += __shfl_xor(s,mm); s2 += __shfl_xor(s2,mm); }
  __shared__ float ps[4], ps2[4];
  const int w = t>>6, l = t&63;
  if (l==0){ ps[w]=s; ps2[w]=s2; }
  __syncthreads();
  s  = ps[0]+ps[1]+ps[2]+ps[3];
  s2 = ps2[0]+ps2[1]+ps2[2]+ps2[3];
  const float mu = s*(1.f/CDIM);
  const float rstd = rsqrtf(s2*(1.f/CDIM) - mu*mu + 1e-5f);
  const float4 gg = ((const float4*)g)[t];
  const float4 bb = ((const float4*)b)[t];
  const float y0=(v.x-mu)*rstd*gg.x+bb.x, y1=(v.y-mu)*rstd*gg.y+bb.y;
  const float y2=(v.z-mu)*rstd*gg.z+bb.z, y3=(v.w-mu)*rstd*gg.w+bb.w;
  s16x4 o; o[0]=f2bf(y0); o[1]=f2bf(y1); o[2]=f2bf(y2); o[3]=f2bf(y3);
  *(s16x4*)(h2 + (long long)row*CDIM + t*4) = o;

  float acc[8];
  const float* wr0 = Wr + (long long)(t*4)*NEXP;
  #pragma unroll
  for (int e=0;e<8;e++) acc[e] = y0*wr0[e] + y1*wr0[8+e] + y2*wr0[16+e] + y3*wr0[24+e];
  #pragma unroll
  for (int mm=1; mm<64; mm<<=1){
    #pragma unroll
    for (int e=0;e<8;e++) acc[e] += __shfl_xor(acc[e], mm);
  }
  __shared__ float pl[4][8];
  if (l==0){
    #pragma unroll
    for (int e=0;e<8;e++) pl[w][e]=acc[e];
  }
  __syncthreads();
  if (t==0){
    float lg[8];
    #pragma unroll
    for (int e=0;e<8;e++) lg[e] = pl[0][e]+pl[1][e]+pl[2][e]+pl[3][e];
    float mx = lg[0];
    #pragma unroll
    for (int e=1;e<8;e++) mx = fmaxf(mx, lg[e]);
    float pr[8]; float sum = 0.f;
    #pragma unroll
    for (int e=0;e<8;e++){ pr[e]=expf(lg[e]-mx); sum += pr[e]; }
    int i0 = 0;
    #pragma unroll
    for (int e=1;e<8;e++) if (pr[e] > pr[i0]) i0 = e;
    int i1 = (i0==0) ? 1 : 0;
    #pragma unroll
    for (int e=0;e<8;e++) if (e!=i0 && pr[e] > pr[i1]) i1 = e;
    const float p0 = pr[i0]/sum, p1 = pr[i1]/sum;
    const float dn = p0 + p1 + 1e-9f;
    tidx[row*2]=i0; tidx[row*2+1]=i1;
    tw[row*2]=p0/dn; tw[row*2+1]=p1/dn;
    atomicAdd(&counts[i0],1); atomicAdd(&counts[i1],1);
  }
}

// ---------------- routing setup (tiny; rowmap pre-initialized by memset 0xFF) -------
__global__ void k_route_setup(const int* __restrict__ counts, int* __restrict__ offs,
                              int* __restrict__ cursors, float* __restrict__ util){
  if (threadIdx.x == 0){
    int o = 0;
    for (int e=0;e<8;e++){
      offs[e] = o; cursors[e] = o;
      o += (counts[e] + 127) & ~127;
    }
    offs[8] = o;
    for (int e=0;e<8;e++) util[e] = (float)counts[e] / 8192.0f;
  }
}

// ---------------- scatter tokens to expert segments ----------------
__global__ void k_scatter(const int* __restrict__ tidx, const float* __restrict__ tw,
                          int* __restrict__ cursors, int* __restrict__ rowmap,
                          float* __restrict__ roww, int* __restrict__ posmap){
  const int i = blockIdx.x*blockDim.x + threadIdx.x;
  if (i >= 2*NTOK) return;
  const int e = tidx[i];
  const int pos = atomicAdd(&cursors[e], 1);
  rowmap[pos] = i >> 1;
  roww[pos]   = tw[i];
  posmap[i]   = pos;
}

// ---------------- GEMM 128x128 (proven): 512 thr, 2-buf, vmcnt(0) ----------
// EPI 0: +bias -> bf16 (QKV) | EPI 1: +bias +resid -> f32 (proj)
// EPI 2: gather + GELU(tanh) -> bf16 (MoE up) | EPI 3: per-expert bias -> bf16 (MoE down)
template<int EPI>
__launch_bounds__(512, 4)
__global__ void k_gemm(const short* __restrict__ A, const short* __restrict__ Bt,
                       const float* __restrict__ bias, const float* __restrict__ resid,
                       void* __restrict__ Cout, int N, int K,
                       const int* __restrict__ rowmap, const int* __restrict__ offs,
                       long long expStrideB, const short* __restrict__ zrow){
  // bijective XCD swizzle (m204)
  int wg = blockIdx.x;
  const int nwg = gridDim.x;
  {
    const int q = nwg >> 3, r8 = nwg & 7;
    const int xcd = wg & 7, pos = wg >> 3;
    wg = (xcd < r8 ? xcd*(q+1) : r8*(q+1) + (xcd - r8)*q) + pos;
  }
  const int gridN = N >> 7;
  const int gridM = nwg / gridN;
  const int mtile = wg % gridM, ntile = wg / gridM;
  const int mbase = mtile*128;
  const int nbase = ntile*128;
  int e = 0;
  if constexpr (EPI >= 2){
    if (mbase >= offs[8]) return;
    while (e < 7 && mbase >= offs[e+1]) e++;
    Bt += (long long)e * expStrideB;
  }
  __shared__ short Asm[2][4096];
  __shared__ short Bsm[2][4096];
  const int tid = threadIdx.x;
  const int w = tid >> 6, l = tid & 63;
  const int wr = w >> 1, wc = w & 1;       // 4M x 2N wave grid
  const int l15 = l & 15, l4 = l >> 4;

  const short* aSrc; const short* bSrc;
  {
    const int r = tid >> 2, ch = tid & 3;
    const int sch = (ch ^ (r >> 1)) & 3;   // source chunk (involution of swz64)
    if constexpr (EPI == 2){
      const int grow = rowmap[mbase + r];
      aSrc = (grow >= 0) ? (A + (long long)grow*K + sch*8) : (zrow + sch*8);
    } else {
      aSrc = A + (long long)(mbase + r)*K + sch*8;
    }
    bSrc = Bt + (long long)(nbase + r)*K + sch*8;
  }
  const int dOff = w*512;                  // wave-uniform shorts offset

  f32x4 acc[2][4];
  const f32x4 z4 = {0.f,0.f,0.f,0.f};
  #pragma unroll
  for (int i=0;i<2;i++){
    #pragma unroll
    for (int jn=0;jn<4;jn++) acc[i][jn] = z4;
  }

  auto stage = [&](int buf, int kt){
    gl16(aSrc + kt, &Asm[buf][dOff]);
    gl16(bSrc + kt, &Bsm[buf][dOff]);
  };
  auto compute = [&](int buf){
    bf16x8 af[2], bfr[4];
    #pragma unroll
    for (int i=0;i<2;i++)
      af[i]  = *(const bf16x8*)((char*)Asm[buf] + swz64(wr*32 + i*16 + l15, l4));
    #pragma unroll
    for (int jn=0;jn<4;jn++)
      bfr[jn] = *(const bf16x8*)((char*)Bsm[buf] + swz64(wc*64 + jn*16 + l15, l4));
    #pragma unroll
    for (int i=0;i<2;i++){
      #pragma unroll
      for (int jn=0;jn<4;jn++)
        acc[i][jn] = __builtin_amdgcn_mfma_f32_16x16x32_bf16(af[i], bfr[jn], acc[i][jn], 0,0,0);
    }
  };

  stage(0, 0);
  asm volatile("s_waitcnt vmcnt(0)" ::: "memory");
  __builtin_amdgcn_s_barrier();

  int cur = 0;
  for (int kt = 32; kt < K; kt += 32){
    stage(cur ^ 1, kt);
    compute(cur);
    asm volatile("s_waitcnt vmcnt(0)" ::: "memory");
    __builtin_amdgcn_s_barrier();
    cur ^= 1;
  }
  compute(cur);

  #pragma unroll
  for (int i=0;i<2;i++){
    const int row0 = mbase + wr*32 + i*16 + l4*4;
    #pragma unroll
    for (int jn=0;jn<4;jn++){
      const int col = nbase + wc*64 + jn*16 + l15;
      const float bi = bias[(EPI>=2 ? e*N : 0) + col];
      #pragma unroll
      for (int j=0;j<4;j++){
        const long long idx = (long long)(row0 + j)*N + col;
        float v = acc[i][jn][j] + bi;
        if constexpr (EPI == 0){
          ((short*)Cout)[idx] = f2bf(v);
        } else if constexpr (EPI == 1){
          ((float*)Cout)[idx] = v + resid[idx];
        } else if constexpr (EPI == 2){
          ((short*)Cout)[idx] = f2bf(gelu_t(v));
        } else {
          ((short*)Cout)[idx] = f2bf(v);
        }
      }
    }
  }
}

// ---------------- flash attention (causal), 128 q rows / block, KVBLK=128 ------------
// 8 waves; waves 0-3 lower q-tile, 4-7 upper. 128 kv rows staged per round (two
// 64-row sub-tiles share one barrier round) -> half the stage/barrier rounds.
__launch_bounds__(512)
__global__ void k_attn(const short* __restrict__ qkv, short* __restrict__ y){
  const int qp = blockIdx.x;       // q pair (128 rows)
  const int bh = blockIdx.y;
  const int bb = bh >> 4;
  const int h  = bh & 15;
  const int tid = threadIdx.x;
  const int w = tid >> 6, l = tid & 63;
  const int half = w >> 2, wq = w & 3;
  const int l15 = l & 15, l4 = l >> 4;

  __shared__ short Ksm[128*64];    // 128 kv rows x 64 d (swz128 rows)
  __shared__ short Vtsm[64*128];   // 64 d rows x 128 kv cols (256B rows, XOR-chunk swz)
  __shared__ short Psm[8*16*64];

  const long long rs = 3*CDIM;
  const int qrow0 = bb*1024 + qp*128;
  const int myQt = (qp << 1) + half;      // my 64-row q-tile index

  bf16x8 aq[2];
  {
    const int qr = qrow0 + half*64 + wq*16 + l15;
    const short* qp2 = qkv + (long long)qr*rs + h*HDIM;
    aq[0] = *(const bf16x8*)(qp2 + l4*8);
    aq[1] = *(const bf16x8*)(qp2 + 32 + l4*8);
  }

  const f32x4 z4 = {0.f,0.f,0.f,0.f};
  f32x4 O[4];
  #pragma unroll
  for (int cf=0;cf<4;cf++) O[cf] = z4;
  float mrow[4], lrow[4];
  #pragma unroll
  for (int j=0;j<4;j++){ mrow[j] = -1e30f; lrow[j] = 0.f; }

  for (int it = 0; it <= qp; ++it){
    const int kvrow0 = bb*1024 + it*128;
    #pragma unroll
    for (int pz=0; pz<2; ++pz){
      const int rr = (tid >> 3) + pz*64;   // kv row 0..127
      const int c = tid & 7;
      const short* kp = qkv + (long long)(kvrow0 + rr)*rs + CDIM + h*HDIM + c*8;
      *(bf16x8*)((char*)Ksm + swz128(rr, c)) = *(const bf16x8*)kp;
      const short* vp = qkv + (long long)(kvrow0 + rr)*rs + 2*CDIM + h*HDIM + c*8;
      bf16x8 vv = *(const bf16x8*)vp;
      #pragma unroll
      for (int i=0;i<8;i++){
        const int d = c*8 + i;
        *(short*)((char*)Vtsm + d*256 + ((((rr>>3) ^ (d&7)) & 15)<<4) + ((2*rr)&15)) = vv[i];
      }
    }
    __syncthreads();

    #pragma unroll
    for (int ks=0; ks<2; ++ks){
      const int kvb = it*2 + ks;
      if (kvb <= myQt){
        f32x4 S[4];
        #pragma unroll
        for (int cf=0;cf<4;cf++) S[cf] = z4;
        #pragma unroll
        for (int cf=0;cf<4;cf++){
          #pragma unroll
          for (int kf=0;kf<2;kf++){
            bf16x8 bk = *(const bf16x8*)((char*)Ksm + swz128(ks*64 + cf*16 + l15, kf*4 + l4));
            S[cf] = __builtin_amdgcn_mfma_f32_16x16x32_bf16(aq[kf], bk, S[cf], 0,0,0);
          }
        }

        const bool diag = (kvb == myQt);
        #pragma unroll
        for (int cf=0;cf<4;cf++){
          #pragma unroll
          for (int j=0;j<4;j++){
            float s = S[cf][j] * 0.125f;
            if (diag && (cf*16 + l15 > wq*16 + l4*4 + j)) s = -1e30f;
            S[cf][j] = s;
          }
        }

        float alpha[4];
        #pragma unroll
        for (int j=0;j<4;j++){
          float mx = fmaxf(fmaxf(S[0][j],S[1][j]), fmaxf(S[2][j],S[3][j]));
          #pragma unroll
          for (int mm=1; mm<16; mm<<=1) mx = fmaxf(mx, __shfl_xor(mx, mm));
          const float mnew = fmaxf(mrow[j], mx);
          const float al = expf(mrow[j] - mnew);
          float psum = 0.f;
          #pragma unroll
          for (int cf=0;cf<4;cf++){ float pp = expf(S[cf][j]-mnew); S[cf][j]=pp; psum += pp; }
          #pragma unroll
          for (int mm=1; mm<16; mm<<=1) psum += __shfl_xor(psum, mm);
          lrow[j] = lrow[j]*al + psum;
          mrow[j] = mnew; alpha[j] = al;
        }
        #pragma unroll
        for (int cf=0;cf<4;cf++){
          #pragma unroll
          for (int j=0;j<4;j++) O[cf][j] *= alpha[j];
        }

        char* pw = (char*)Psm + w*2048;
        #pragma unroll
        for (int cf=0;cf<4;cf++){
          #pragma unroll
          for (int j=0;j<4;j++){
            const int r = l4*4 + j;
            const int cb = (cf*16 + l15)*2;
            *(short*)(pw + r*128 + ((((cb>>4) ^ r) & 7)<<4) + (cb & 15)) = f2bf(S[cf][j]);
          }
        }
        bf16x8 pa[2];
        pa[0] = *(const bf16x8*)(pw + swz128(l15, l4));
        pa[1] = *(const bf16x8*)(pw + swz128(l15, 4 + l4));
        #pragma unroll
        for (int cf=0;cf<4;cf++){
          const int d = cf*16 + l15;
          #pragma unroll
          for (int kf=0;kf<2;kf++){
            const int ch = ks*8 + kf*4 + l4;
            bf16x8 bv = *(const bf16x8*)((char*)Vtsm + d*256 + (((ch ^ (d&7)) & 15)<<4));
            O[cf] = __builtin_amdgcn_mfma_f32_16x16x32_bf16(pa[kf], bv, O[cf], 0,0,0);
          }
        }
      }
    }
    __syncthreads();
  }

  const int yr0 = qrow0 + half*64 + wq*16;
  #pragma unroll
  for (int cf=0;cf<4;cf++){
    #pragma unroll
    for (int j=0;j<4;j++){
      const int r = l4*4 + j;
      y[(long long)(yr0 + r)*CDIM + h*HDIM + cf*16 + l15] = f2bf(O[cf][j] / lrow[j]);
    }
  }
}

// ---------------- final combine: out = x1 + w0*eo[p0] + w1*eo[p1] (eo bf16) ---------
__global__ void k_combine(const float* __restrict__ x1, const short* __restrict__ eo,
                          const int* __restrict__ posmap, const float* __restrict__ roww,
                          float* __restrict__ out){
  const int row = blockIdx.x;
  const int t = threadIdx.x;
  const int p0 = posmap[row*2], p1 = posmap[row*2+1];
  const float w0 = roww[p0], w1 = roww[p1];
  const float4 a  = ((const float4*)(x1 + (long long)row*CDIM))[t];
  const s16x4 e0 = *(const s16x4*)(eo + (long long)p0*CDIM + t*4);
  const s16x4 e1 = *(const s16x4*)(eo + (long long)p1*CDIM + t*4);
  float4 r;
  r.x = a.x + w0*bf2f(e0[0]) + w1*bf2f(e1[0]);
  r.y = a.y + w0*bf2f(e0[1]) + w1*bf2f(e1[1]);
  r.z = a.z + w0*bf2f(e0[2]) + w1*bf2f(e1[2]);
  r.w = a.w + w0*bf2f(e0[3]) + w1*bf2f(e1[3]);
  ((float4*)(out + (long long)row*CDIM))[t] = r;
}

extern "C" void kernel_launch(void* const* d_in, const int* in_sizes, int n_in,
                              void* d_out, int out_size, void* d_ws, size_t ws_size,
                              hipStream_t stream){
  const float* x     = (const float*)d_in[0];
  const float* ln1_g = (const float*)d_in[1];
  const float* ln1_b = (const float*)d_in[2];
  const float* W_qkv = (const float*)d_in[3];
  const float* b_qkv = (const float*)d_in[4];
  const float* W_proj= (const float*)d_in[5];
  const float* b_proj= (const float*)d_in[6];
  const float* ln2_g = (const float*)d_in[7];
  const float* ln2_b = (const float*)d_in[8];
  const float* W_r   = (const float*)d_in[9];
  const float* W1    = (const float*)d_in[10];
  const float* b1    = (const float*)d_in[11];
  const float* W2    = (const float*)d_in[12];
  const float* b2    = (const float*)d_in[13];
  float* out = (float*)d_out;
  float* util = out + (long long)NTOK*CDIM;

  char* p = (char*)d_ws;
  auto alloc = [&](size_t bytes)->char*{
    char* r = p; p += (bytes + 255) & ~(size_t)255; return r;
  };
  // persistent region
  short* Wt1   = (short*)alloc((size_t)NEXP*HIDD*CDIM*2);
  short* Wt2   = (short*)alloc((size_t)NEXP*CDIM*HIDD*2);
  float* x1    = (float*)alloc((size_t)NTOK*CDIM*4);
  short* h2    = (short*)alloc((size_t)NTOK*CDIM*2);
  short* hid   = (short*)alloc((size_t)MAXROWS*HIDD*2);
  int*   tidx  = (int*)alloc(2*NTOK*4);
  float* tw    = (float*)alloc(2*NTOK*4);
  int*   counts= (int*)alloc(256);
  int*   offs  = (int*)alloc(256);
  int*   curs  = (int*)alloc(256);
  int*   rowmap= (int*)alloc(MAXROWS*4);
  float* roww  = (float*)alloc(MAXROWS*4);
  int*   posmap= (int*)alloc(2*NTOK*4);
  short* zrow  = (short*)alloc(8192);
  // transient region (dead after proj GEMM) -- eo aliases it afterwards
  char* transStart = p;
  short* WtQ = (short*)alloc((size_t)3*CDIM*CDIM*2);
  short* WtP = (short*)alloc((size_t)CDIM*CDIM*2);
  short* h   = (short*)alloc((size_t)NTOK*CDIM*2);
  short* qkv = (short*)alloc((size_t)NTOK*3*CDIM*2);
  short* y   = (short*)alloc((size_t)NTOK*CDIM*2);
  short* eo  = (short*)transStart;  // MAXROWS*CDIM*2 = 18.9MB <= transient

  (void)hipMemsetAsync(counts, 0, 32, stream);
  (void)hipMemsetAsync(zrow, 0, 8192, stream);
  (void)hipMemsetAsync(rowmap, 0xFF, MAXROWS*4, stream);

  k_transpose_cast<<<dim3(3*CDIM/64, CDIM/64, 1), 256, 0, stream>>>(W_qkv, WtQ, CDIM, 3*CDIM);
  k_transpose_cast<<<dim3(CDIM/64, CDIM/64, 1),   256, 0, stream>>>(W_proj, WtP, CDIM, CDIM);
  k_transpose_cast<<<dim3(HIDD/64, CDIM/64, NEXP),256, 0, stream>>>(W1, Wt1, CDIM, HIDD);
  k_transpose_cast<<<dim3(CDIM/64, HIDD/64, NEXP),256, 0, stream>>>(W2, Wt2, HIDD, CDIM);

  k_ln1<<<NTOK, 256, 0, stream>>>(x, ln1_g, ln1_b, h);

  k_gemm<0><<<dim3((NTOK/128)*(3*CDIM/128)), 512, 0, stream>>>(
      h, WtQ, b_qkv, nullptr, qkv, 3*CDIM, CDIM, nullptr, nullptr, 0, nullptr);

  k_attn<<<dim3(1024/128, 4*NHEAD), 512, 0, stream>>>(qkv, y);

  k_gemm<1><<<dim3((NTOK/128)*(CDIM/128)), 512, 0, stream>>>(
      y, WtP, b_proj, x, x1, CDIM, CDIM, nullptr, nullptr, 0, nullptr);

  k_ln2_router<<<NTOK, 256, 0, stream>>>(x1, ln2_g, ln2_b, W_r, h2, tidx, tw, counts);
  k_route_setup<<<1, 64, 0, stream>>>(counts, offs, curs, util);
  k_scatter<<<(2*NTOK)/256, 256, 0, stream>>>(tidx, tw, curs, rowmap, roww, posmap);

  k_gemm<2><<<dim3((MAXROWS/128)*(HIDD/128)), 512, 0, stream>>>(
      h2, Wt1, b1, nullptr, hid, HIDD, CDIM, rowmap, offs, (long long)HIDD*CDIM, zrow);
  k_gemm<3><<<dim3((MAXROWS/128)*(CDIM/128)), 512, 0, stream>>>(
      hid, Wt2, b2, nullptr, eo, CDIM, HIDD, nullptr, offs, (long long)CDIM*HIDD, zrow);

  k_combine<<<NTOK, 256, 0, stream>>>(x1, eo, posmap, roww, out);
}

// Round 14
// 607.787 us; speedup vs baseline: 1.0481x; 1.0317x over previous
//
#include <hip/hip_runtime.h>
#include <cmath>

#define CDIM 1024
#define NTOK 4096
#define NHEAD 16
#define HDIM 64
#define NEXP 8
#define HIDD 4096
#define MAXROWS 9216   // 72 tiles * 128

typedef short bf16x8 __attribute__((ext_vector_type(8)));
typedef short s16x4  __attribute__((ext_vector_type(4)));
typedef float f32x4  __attribute__((ext_vector_type(4)));

static __device__ __forceinline__ short f2bf(float f){
  unsigned u = __builtin_bit_cast(unsigned, f);
  u += 0x7fffu + ((u >> 16) & 1u);
  return (short)(u >> 16);
}
static __device__ __forceinline__ float bf2f(short s){
  unsigned u = ((unsigned)(unsigned short)s) << 16;
  return __builtin_bit_cast(float, u);
}
// tanh-form GELU (|diff vs exact erf-GELU| <= ~3e-3, well within threshold)
static __device__ __forceinline__ float gelu_t(float x){
  const float y = 0.7978845608f*(x + 0.044715f*x*x*x);
  const float e = __expf(2.f*y);
  return 0.5f*x*(1.f + (e-1.f)/(e+1.f));
}

// swizzle for 64-byte rows (32 bf16), 16B chunks ch=0..3 (measured 0-conflict)
static __device__ __forceinline__ int swz64(int r, int ch){
  return r*64 + (((ch ^ (r>>1)) & 3) << 4);
}
// swizzle for 128-byte rows (64 bf16), 16B chunks ch=0..7
static __device__ __forceinline__ int swz128(int r, int ch){
  return r*128 + (((ch ^ r) & 7) << 4);
}

// async 16B global->LDS; lds base must be wave-uniform, HW adds lane*16
static __device__ __forceinline__ void gl16(const short* g, short* l){
  __builtin_amdgcn_global_load_lds(
      (const __attribute__((address_space(1))) void*)g,
      (__attribute__((address_space(3))) void*)l, 16, 0, 0);
}

// ---------------- transpose + fp32->bf16 cast:  out[c][r] = in[r][c] ----------------
__global__ void k_transpose_cast(const float* __restrict__ in, short* __restrict__ out,
                                 int R, int Cc){
  __shared__ float tile[64][65];
  const int z = blockIdx.z;
  const float* src = in + (long long)z*R*Cc;
  short* dst = out + (long long)z*R*Cc;
  const int r0 = blockIdx.y*64, c0 = blockIdx.x*64;
  const int t = threadIdx.x;
  #pragma unroll
  for (int it=0; it<4; ++it){
    const int item = t + it*256;
    const int r = item>>4, c4 = item&15;
    const float4 v = *(const float4*)(src + (long long)(r0+r)*Cc + c0 + c4*4);
    tile[r][c4*4+0]=v.x; tile[r][c4*4+1]=v.y; tile[r][c4*4+2]=v.z; tile[r][c4*4+3]=v.w;
  }
  __syncthreads();
  #pragma unroll
  for (int it=0; it<2; ++it){
    const int item = t + it*256;
    const int rr8 = item & 7, cc = item >> 3;
    bf16x8 o;
    #pragma unroll
    for (int i=0;i<8;i++) o[i] = f2bf(tile[rr8*8+i][cc]);
    *(bf16x8*)(dst + (long long)(c0+cc)*R + r0 + rr8*8) = o;
  }
}

// ---------------- LayerNorm 1 -> bf16 ----------------
__global__ void k_ln1(const float* __restrict__ x, const float* __restrict__ g,
                      const float* __restrict__ b, short* __restrict__ out){
  const int row = blockIdx.x;
  const int t = threadIdx.x;
  const float4 v = ((const float4*)(x + (long long)row*CDIM))[t];
  float s  = v.x+v.y+v.z+v.w;
  float s2 = v.x*v.x+v.y*v.y+v.z*v.z+v.w*v.w;
  #pragma unroll
  for (int mm=1; mm<64; mm<<=1){ s += __shfl_xor(s,mm); s2 += __shfl_xor(s2,mm); }
  __shared__ float ps[4], ps2[4];
  const int w = t>>6, l = t&63;
  if (l==0){ ps[w]=s; ps2[w]=s2; }
  __syncthreads();
  s  = ps[0]+ps[1]+ps[2]+ps[3];
  s2 = ps2[0]+ps2[1]+ps2[2]+ps2[3];
  const float mu = s*(1.f/CDIM);
  const float rstd = rsqrtf(s2*(1.f/CDIM) - mu*mu + 1e-5f);
  const float4 gg = ((const float4*)g)[t];
  const float4 bb = ((const float4*)b)[t];
  s16x4 o;
  o[0]=f2bf((v.x-mu)*rstd*gg.x+bb.x); o[1]=f2bf((v.y-mu)*rstd*gg.y+bb.y);
  o[2]=f2bf((v.z-mu)*rstd*gg.z+bb.z); o[3]=f2bf((v.w-mu)*rstd*gg.w+bb.w);
  *(s16x4*)(out + (long long)row*CDIM + t*4) = o;
}

// ---------------- LayerNorm 2 + router (fp32 logits) ----------------
__global__ void k_ln2_router(const float* __restrict__ x1, const float* __restrict__ g,
                             const float* __restrict__ b, const float* __restrict__ Wr,
                             short* __restrict__ h2, int* __restrict__ tidx,
                             float* __restrict__ tw, int* __restrict__ counts){
  const int row = blockIdx.x;
  const int t = threadIdx.x;
  const float4 v = ((const float4*)(x1 + (long long)row*CDIM))[t];
  float s  = v.x+v.y+v.z+v.w;
  float s2 = v.x*v.x+v.y*v.y+v.z*v.z+v.w*v.w;
  #pragma unroll
  for (int mm=1; mm<64; mm<<=1){ s += __shfl_xor(s,mm); s2 += __shfl_xor(s2,mm); }
  __shared__ float ps[4], ps2[4];
  const int w = t>>6, l = t&63;
  if (l==0){ ps[w]=s; ps2[w]=s2; }
  __syncthreads();
  s  = ps[0]+ps[1]+ps[2]+ps[3];
  s2 = ps2[0]+ps2[1]+ps2[2]+ps2[3];
  const float mu = s*(1.f/CDIM);
  const float rstd = rsqrtf(s2*(1.f/CDIM) - mu*mu + 1e-5f);
  const float4 gg = ((const float4*)g)[t];
  const float4 bb = ((const float4*)b)[t];
  const float y0=(v.x-mu)*rstd*gg.x+bb.x, y1=(v.y-mu)*rstd*gg.y+bb.y;
  const float y2=(v.z-mu)*rstd*gg.z+bb.z, y3=(v.w-mu)*rstd*gg.w+bb.w;
  s16x4 o; o[0]=f2bf(y0); o[1]=f2bf(y1); o[2]=f2bf(y2); o[3]=f2bf(y3);
  *(s16x4*)(h2 + (long long)row*CDIM + t*4) = o;

  float acc[8];
  const float* wr0 = Wr + (long long)(t*4)*NEXP;
  #pragma unroll
  for (int e=0;e<8;e++) acc[e] = y0*wr0[e] + y1*wr0[8+e] + y2*wr0[16+e] + y3*wr0[24+e];
  #pragma unroll
  for (int mm=1; mm<64; mm<<=1){
    #pragma unroll
    for (int e=0;e<8;e++) acc[e] += __shfl_xor(acc[e], mm);
  }
  __shared__ float pl[4][8];
  if (l==0){
    #pragma unroll
    for (int e=0;e<8;e++) pl[w][e]=acc[e];
  }
  __syncthreads();
  if (t==0){
    float lg[8];
    #pragma unroll
    for (int e=0;e<8;e++) lg[e] = pl[0][e]+pl[1][e]+pl[2][e]+pl[3][e];
    float mx = lg[0];
    #pragma unroll
    for (int e=1;e<8;e++) mx = fmaxf(mx, lg[e]);
    float pr[8]; float sum = 0.f;
    #pragma unroll
    for (int e=0;e<8;e++){ pr[e]=expf(lg[e]-mx); sum += pr[e]; }
    int i0 = 0;
    #pragma unroll
    for (int e=1;e<8;e++) if (pr[e] > pr[i0]) i0 = e;
    int i1 = (i0==0) ? 1 : 0;
    #pragma unroll
    for (int e=0;e<8;e++) if (e!=i0 && pr[e] > pr[i1]) i1 = e;
    const float p0 = pr[i0]/sum, p1 = pr[i1]/sum;
    const float dn = p0 + p1 + 1e-9f;
    tidx[row*2]=i0; tidx[row*2+1]=i1;
    tw[row*2]=p0/dn; tw[row*2+1]=p1/dn;
    atomicAdd(&counts[i0],1); atomicAdd(&counts[i1],1);
  }
}

// ---------------- scatter + inline route-setup ----------------
// Every block recomputes the per-expert prefix from counts (deterministic);
// pos = offs[e] + atomicAdd(curs0[e]) with curs0 pre-zeroed. Block 0 publishes
// offs (consumed by the MoE GEMMs, ordered by stream) and util.
__global__ void k_scatter(const int* __restrict__ tidx, const float* __restrict__ tw,
                          const int* __restrict__ counts, int* __restrict__ curs0,
                          int* __restrict__ offs, float* __restrict__ util,
                          int* __restrict__ rowmap, float* __restrict__ roww,
                          int* __restrict__ posmap){
  __shared__ int soff[9];
  if (threadIdx.x == 0){
    int o = 0;
    for (int e=0;e<8;e++){
      soff[e] = o;
      o += (counts[e] + 127) & ~127;
    }
    soff[8] = o;
    if (blockIdx.x == 0){
      for (int e=0;e<9;e++) offs[e] = soff[e];
      for (int e=0;e<8;e++) util[e] = (float)counts[e] / 8192.0f;
    }
  }
  __syncthreads();
  const int i = blockIdx.x*blockDim.x + threadIdx.x;
  if (i >= 2*NTOK) return;
  const int e = tidx[i];
  const int pos = soff[e] + atomicAdd(&curs0[e], 1);
  rowmap[pos] = i >> 1;
  roww[pos]   = tw[i];
  posmap[i]   = pos;
}

// ---------------- GEMM 128x128 (proven): 512 thr, 2-buf, vmcnt(0) ----------
// mtile-major mapping: consecutive wg share the A strip (1 MB), stream B ->
// A panel fetched ~once instead of once per N-column (down: 600 MB nominal -> ~140).
// EPI 0: +bias -> bf16 (QKV) | EPI 1: +bias +resid -> f32 (proj)
// EPI 2: gather + GELU(tanh) -> bf16 (MoE up) | EPI 3: per-expert bias -> bf16 (MoE down)
template<int EPI>
__launch_bounds__(512, 4)
__global__ void k_gemm(const short* __restrict__ A, const short* __restrict__ Bt,
                       const float* __restrict__ bias, const float* __restrict__ resid,
                       void* __restrict__ Cout, int N, int K,
                       const int* __restrict__ rowmap, const int* __restrict__ offs,
                       long long expStrideB, const short* __restrict__ zrow){
  // bijective XCD swizzle (m204)
  int wg = blockIdx.x;
  const int nwg = gridDim.x;
  {
    const int q = nwg >> 3, r8 = nwg & 7;
    const int xcd = wg & 7, pos = wg >> 3;
    wg = (xcd < r8 ? xcd*(q+1) : r8*(q+1) + (xcd - r8)*q) + pos;
  }
  const int gridN = N >> 7;
  const int mtile = wg / gridN, ntile = wg % gridN;   // mtile-major
  const int mbase = mtile*128;
  const int nbase = ntile*128;
  int e = 0;
  if constexpr (EPI >= 2){
    if (mbase >= offs[8]) return;
    while (e < 7 && mbase >= offs[e+1]) e++;
    Bt += (long long)e * expStrideB;
  }
  __shared__ short Asm[2][4096];
  __shared__ short Bsm[2][4096];
  const int tid = threadIdx.x;
  const int w = tid >> 6, l = tid & 63;
  const int wr = w >> 1, wc = w & 1;       // 4M x 2N wave grid
  const int l15 = l & 15, l4 = l >> 4;

  const short* aSrc; const short* bSrc;
  {
    const int r = tid >> 2, ch = tid & 3;
    const int sch = (ch ^ (r >> 1)) & 3;   // source chunk (involution of swz64)
    if constexpr (EPI == 2){
      const int grow = rowmap[mbase + r];
      aSrc = (grow >= 0) ? (A + (long long)grow*K + sch*8) : (zrow + sch*8);
    } else {
      aSrc = A + (long long)(mbase + r)*K + sch*8;
    }
    bSrc = Bt + (long long)(nbase + r)*K + sch*8;
  }
  const int dOff = w*512;                  // wave-uniform shorts offset

  f32x4 acc[2][4];
  const f32x4 z4 = {0.f,0.f,0.f,0.f};
  #pragma unroll
  for (int i=0;i<2;i++){
    #pragma unroll
    for (int jn=0;jn<4;jn++) acc[i][jn] = z4;
  }

  auto stage = [&](int buf, int kt){
    gl16(aSrc + kt, &Asm[buf][dOff]);
    gl16(bSrc + kt, &Bsm[buf][dOff]);
  };
  auto compute = [&](int buf){
    bf16x8 af[2], bfr[4];
    #pragma unroll
    for (int i=0;i<2;i++)
      af[i]  = *(const bf16x8*)((char*)Asm[buf] + swz64(wr*32 + i*16 + l15, l4));
    #pragma unroll
    for (int jn=0;jn<4;jn++)
      bfr[jn] = *(const bf16x8*)((char*)Bsm[buf] + swz64(wc*64 + jn*16 + l15, l4));
    #pragma unroll
    for (int i=0;i<2;i++){
      #pragma unroll
      for (int jn=0;jn<4;jn++)
        acc[i][jn] = __builtin_amdgcn_mfma_f32_16x16x32_bf16(af[i], bfr[jn], acc[i][jn], 0,0,0);
    }
  };

  stage(0, 0);
  asm volatile("s_waitcnt vmcnt(0)" ::: "memory");
  __builtin_amdgcn_s_barrier();

  int cur = 0;
  for (int kt = 32; kt < K; kt += 32){
    stage(cur ^ 1, kt);
    compute(cur);
    asm volatile("s_waitcnt vmcnt(0)" ::: "memory");
    __builtin_amdgcn_s_barrier();
    cur ^= 1;
  }
  compute(cur);

  #pragma unroll
  for (int i=0;i<2;i++){
    const int row0 = mbase + wr*32 + i*16 + l4*4;
    #pragma unroll
    for (int jn=0;jn<4;jn++){
      const int col = nbase + wc*64 + jn*16 + l15;
      const float bi = bias[(EPI>=2 ? e*N : 0) + col];
      #pragma unroll
      for (int j=0;j<4;j++){
        const long long idx = (long long)(row0 + j)*N + col;
        float v = acc[i][jn][j] + bi;
        if constexpr (EPI == 0){
          ((short*)Cout)[idx] = f2bf(v);
        } else if constexpr (EPI == 1){
          ((float*)Cout)[idx] = v + resid[idx];
        } else if constexpr (EPI == 2){
          ((short*)Cout)[idx] = f2bf(gelu_t(v));
        } else {
          ((short*)Cout)[idx] = f2bf(v);
        }
      }
    }
  }
}

// ---------------- flash attention (causal), 128 q rows / block, KVBLK=128 ------------
__launch_bounds__(512)
__global__ void k_attn(const short* __restrict__ qkv, short* __restrict__ y){
  const int qp = blockIdx.x;       // q pair (128 rows)
  const int bh = blockIdx.y;
  const int bb = bh >> 4;
  const int h  = bh & 15;
  const int tid = threadIdx.x;
  const int w = tid >> 6, l = tid & 63;
  const int half = w >> 2, wq = w & 3;
  const int l15 = l & 15, l4 = l >> 4;

  __shared__ short Ksm[128*64];    // 128 kv rows x 64 d (swz128 rows)
  __shared__ short Vtsm[64*128];   // 64 d rows x 128 kv cols (256B rows, XOR-chunk swz)
  __shared__ short Psm[8*16*64];

  const long long rs = 3*CDIM;
  const int qrow0 = bb*1024 + qp*128;
  const int myQt = (qp << 1) + half;      // my 64-row q-tile index

  bf16x8 aq[2];
  {
    const int qr = qrow0 + half*64 + wq*16 + l15;
    const short* qp2 = qkv + (long long)qr*rs + h*HDIM;
    aq[0] = *(const bf16x8*)(qp2 + l4*8);
    aq[1] = *(const bf16x8*)(qp2 + 32 + l4*8);
  }

  const f32x4 z4 = {0.f,0.f,0.f,0.f};
  f32x4 O[4];
  #pragma unroll
  for (int cf=0;cf<4;cf++) O[cf] = z4;
  float mrow[4], lrow[4];
  #pragma unroll
  for (int j=0;j<4;j++){ mrow[j] = -1e30f; lrow[j] = 0.f; }

  for (int it = 0; it <= qp; ++it){
    const int kvrow0 = bb*1024 + it*128;
    #pragma unroll
    for (int pz=0; pz<2; ++pz){
      const int rr = (tid >> 3) + pz*64;   // kv row 0..127
      const int c = tid & 7;
      const short* kp = qkv + (long long)(kvrow0 + rr)*rs + CDIM + h*HDIM + c*8;
      *(bf16x8*)((char*)Ksm + swz128(rr, c)) = *(const bf16x8*)kp;
      const short* vp = qkv + (long long)(kvrow0 + rr)*rs + 2*CDIM + h*HDIM + c*8;
      bf16x8 vv = *(const bf16x8*)vp;
      #pragma unroll
      for (int i=0;i<8;i++){
        const int d = c*8 + i;
        *(short*)((char*)Vtsm + d*256 + ((((rr>>3) ^ (d&7)) & 15)<<4) + ((2*rr)&15)) = vv[i];
      }
    }
    __syncthreads();

    #pragma unroll
    for (int ks=0; ks<2; ++ks){
      const int kvb = it*2 + ks;
      if (kvb <= myQt){
        f32x4 S[4];
        #pragma unroll
        for (int cf=0;cf<4;cf++) S[cf] = z4;
        #pragma unroll
        for (int cf=0;cf<4;cf++){
          #pragma unroll
          for (int kf=0;kf<2;kf++){
            bf16x8 bk = *(const bf16x8*)((char*)Ksm + swz128(ks*64 + cf*16 + l15, kf*4 + l4));
            S[cf] = __builtin_amdgcn_mfma_f32_16x16x32_bf16(aq[kf], bk, S[cf], 0,0,0);
          }
        }

        const bool diag = (kvb == myQt);
        #pragma unroll
        for (int cf=0;cf<4;cf++){
          #pragma unroll
          for (int j=0;j<4;j++){
            float s = S[cf][j] * 0.125f;
            if (diag && (cf*16 + l15 > wq*16 + l4*4 + j)) s = -1e30f;
            S[cf][j] = s;
          }
        }

        float alpha[4];
        #pragma unroll
        for (int j=0;j<4;j++){
          float mx = fmaxf(fmaxf(S[0][j],S[1][j]), fmaxf(S[2][j],S[3][j]));
          #pragma unroll
          for (int mm=1; mm<16; mm<<=1) mx = fmaxf(mx, __shfl_xor(mx, mm));
          const float mnew = fmaxf(mrow[j], mx);
          const float al = expf(mrow[j] - mnew);
          float psum = 0.f;
          #pragma unroll
          for (int cf=0;cf<4;cf++){ float pp = expf(S[cf][j]-mnew); S[cf][j]=pp; psum += pp; }
          #pragma unroll
          for (int mm=1; mm<16; mm<<=1) psum += __shfl_xor(psum, mm);
          lrow[j] = lrow[j]*al + psum;
          mrow[j] = mnew; alpha[j] = al;
        }
        #pragma unroll
        for (int cf=0;cf<4;cf++){
          #pragma unroll
          for (int j=0;j<4;j++) O[cf][j] *= alpha[j];
        }

        char* pw = (char*)Psm + w*2048;
        #pragma unroll
        for (int cf=0;cf<4;cf++){
          #pragma unroll
          for (int j=0;j<4;j++){
            const int r = l4*4 + j;
            const int cb = (cf*16 + l15)*2;
            *(short*)(pw + r*128 + ((((cb>>4) ^ r) & 7)<<4) + (cb & 15)) = f2bf(S[cf][j]);
          }
        }
        bf16x8 pa[2];
        pa[0] = *(const bf16x8*)(pw + swz128(l15, l4));
        pa[1] = *(const bf16x8*)(pw + swz128(l15, 4 + l4));
        #pragma unroll
        for (int cf=0;cf<4;cf++){
          const int d = cf*16 + l15;
          #pragma unroll
          for (int kf=0;kf<2;kf++){
            const int ch = ks*8 + kf*4 + l4;
            bf16x8 bv = *(const bf16x8*)((char*)Vtsm + d*256 + (((ch ^ (d&7)) & 15)<<4));
            O[cf] = __builtin_amdgcn_mfma_f32_16x16x32_bf16(pa[kf], bv, O[cf], 0,0,0);
          }
        }
      }
    }
    __syncthreads();
  }

  const int yr0 = qrow0 + half*64 + wq*16;
  #pragma unroll
  for (int cf=0;cf<4;cf++){
    #pragma unroll
    for (int j=0;j<4;j++){
      const int r = l4*4 + j;
      y[(long long)(yr0 + r)*CDIM + h*HDIM + cf*16 + l15] = f2bf(O[cf][j] / lrow[j]);
    }
  }
}

// ---------------- final combine: out = x1 + w0*eo[p0] + w1*eo[p1] (eo bf16) ---------
__global__ void k_combine(const float* __restrict__ x1, const short* __restrict__ eo,
                          const int* __restrict__ posmap, const float* __restrict__ roww,
                          float* __restrict__ out){
  const int row = blockIdx.x;
  const int t = threadIdx.x;
  const int p0 = posmap[row*2], p1 = posmap[row*2+1];
  const float w0 = roww[p0], w1 = roww[p1];
  const float4 a  = ((const float4*)(x1 + (long long)row*CDIM))[t];
  const s16x4 e0 = *(const s16x4*)(eo + (long long)p0*CDIM + t*4);
  const s16x4 e1 = *(const s16x4*)(eo + (long long)p1*CDIM + t*4);
  float4 r;
  r.x = a.x + w0*bf2f(e0[0]) + w1*bf2f(e1[0]);
  r.y = a.y + w0*bf2f(e0[1]) + w1*bf2f(e1[1]);
  r.z = a.z + w0*bf2f(e0[2]) + w1*bf2f(e1[2]);
  r.w = a.w + w0*bf2f(e0[3]) + w1*bf2f(e1[3]);
  ((float4*)(out + (long long)row*CDIM))[t] = r;
}

extern "C" void kernel_launch(void* const* d_in, const int* in_sizes, int n_in,
                              void* d_out, int out_size, void* d_ws, size_t ws_size,
                              hipStream_t stream){
  const float* x     = (const float*)d_in[0];
  const float* ln1_g = (const float*)d_in[1];
  const float* ln1_b = (const float*)d_in[2];
  const float* W_qkv = (const float*)d_in[3];
  const float* b_qkv = (const float*)d_in[4];
  const float* W_proj= (const float*)d_in[5];
  const float* b_proj= (const float*)d_in[6];
  const float* ln2_g = (const float*)d_in[7];
  const float* ln2_b = (const float*)d_in[8];
  const float* W_r   = (const float*)d_in[9];
  const float* W1    = (const float*)d_in[10];
  const float* b1    = (const float*)d_in[11];
  const float* W2    = (const float*)d_in[12];
  const float* b2    = (const float*)d_in[13];
  float* out = (float*)d_out;
  float* util = out + (long long)NTOK*CDIM;

  char* p = (char*)d_ws;
  auto alloc = [&](size_t bytes)->char*{
    char* r = p; p += (bytes + 255) & ~(size_t)255; return r;
  };
  // persistent region
  short* Wt1   = (short*)alloc((size_t)NEXP*HIDD*CDIM*2);
  short* Wt2   = (short*)alloc((size_t)NEXP*CDIM*HIDD*2);
  float* x1    = (float*)alloc((size_t)NTOK*CDIM*4);
  short* h2    = (short*)alloc((size_t)NTOK*CDIM*2);
  short* hid   = (short*)alloc((size_t)MAXROWS*HIDD*2);
  int*   tidx  = (int*)alloc(2*NTOK*4);
  float* tw    = (float*)alloc(2*NTOK*4);
  int*   counts= (int*)alloc(256);
  int*   offs  = (int*)alloc(256);
  int*   curs  = (int*)alloc(256);
  int*   rowmap= (int*)alloc(MAXROWS*4);
  float* roww  = (float*)alloc(MAXROWS*4);
  int*   posmap= (int*)alloc(2*NTOK*4);
  short* zrow  = (short*)alloc(8192);
  // transient region (dead after proj GEMM) -- eo aliases it afterwards
  char* transStart = p;
  short* WtQ = (short*)alloc((size_t)3*CDIM*CDIM*2);
  short* WtP = (short*)alloc((size_t)CDIM*CDIM*2);
  short* h   = (short*)alloc((size_t)NTOK*CDIM*2);
  short* qkv = (short*)alloc((size_t)NTOK*3*CDIM*2);
  short* y   = (short*)alloc((size_t)NTOK*CDIM*2);
  short* eo  = (short*)transStart;  // MAXROWS*CDIM*2 = 18.9MB <= transient

  (void)hipMemsetAsync(counts, 0, 32, stream);
  (void)hipMemsetAsync(curs, 0, 32, stream);
  (void)hipMemsetAsync(zrow, 0, 8192, stream);
  (void)hipMemsetAsync(rowmap, 0xFF, MAXROWS*4, stream);

  k_transpose_cast<<<dim3(3*CDIM/64, CDIM/64, 1), 256, 0, stream>>>(W_qkv, WtQ, CDIM, 3*CDIM);
  k_transpose_cast<<<dim3(CDIM/64, CDIM/64, 1),   256, 0, stream>>>(W_proj, WtP, CDIM, CDIM);
  k_transpose_cast<<<dim3(HIDD/64, CDIM/64, NEXP),256, 0, stream>>>(W1, Wt1, CDIM, HIDD);
  k_transpose_cast<<<dim3(CDIM/64, HIDD/64, NEXP),256, 0, stream>>>(W2, Wt2, HIDD, CDIM);

  k_ln1<<<NTOK, 256, 0, stream>>>(x, ln1_g, ln1_b, h);

  k_gemm<0><<<dim3((NTOK/128)*(3*CDIM/128)), 512, 0, stream>>>(
      h, WtQ, b_qkv, nullptr, qkv, 3*CDIM, CDIM, nullptr, nullptr, 0, nullptr);

  k_attn<<<dim3(1024/128, 4*NHEAD), 512, 0, stream>>>(qkv, y);

  k_gemm<1><<<dim3((NTOK/128)*(CDIM/128)), 512, 0, stream>>>(
      y, WtP, b_proj, x, x1, CDIM, CDIM, nullptr, nullptr, 0, nullptr);

  k_ln2_router<<<NTOK, 256, 0, stream>>>(x1, ln2_g, ln2_b, W_r, h2, tidx, tw, counts);
  k_scatter<<<(2*NTOK)/256, 256, 0, stream>>>(tidx, tw, counts, curs, offs, util,
                                              rowmap, roww, posmap);

  k_gemm<2><<<dim3((MAXROWS/128)*(HIDD/128)), 512, 0, stream>>>(
      h2, Wt1, b1, nullptr, hid, HIDD, CDIM, rowmap, offs, (long long)HIDD*CDIM, zrow);
  k_gemm<3><<<dim3((MAXROWS/128)*(CDIM/128)), 512, 0, stream>>>(
      hid, Wt2, b2, nullptr, eo, CDIM, HIDD, nullptr, offs, (long long)CDIM*HIDD, zrow);

  k_combine<<<NTOK, 256, 0, stream>>>(x1, eo, posmap, roww, out);
}

// Round 15
// 594.552 us; speedup vs baseline: 1.0714x; 1.0223x over previous
//
#include <hip/hip_runtime.h>
#include <cmath>

#define CDIM 1024
#define NTOK 4096
#define NHEAD 16
#define HDIM 64
#define NEXP 8
#define HIDD 4096
#define MAXROWS 9216   // 72 tiles * 128

typedef short bf16x8 __attribute__((ext_vector_type(8)));
typedef short s16x4  __attribute__((ext_vector_type(4)));
typedef float f32x4  __attribute__((ext_vector_type(4)));

static __device__ __forceinline__ short f2bf(float f){
  unsigned u = __builtin_bit_cast(unsigned, f);
  u += 0x7fffu + ((u >> 16) & 1u);
  return (short)(u >> 16);
}
static __device__ __forceinline__ float bf2f(short s){
  unsigned u = ((unsigned)(unsigned short)s) << 16;
  return __builtin_bit_cast(float, u);
}
// tanh-form GELU (|diff vs exact erf-GELU| <= ~3e-3, well within threshold)
static __device__ __forceinline__ float gelu_t(float x){
  const float y = 0.7978845608f*(x + 0.044715f*x*x*x);
  const float e = __expf(2.f*y);
  return 0.5f*x*(1.f + (e-1.f)/(e+1.f));
}

// swizzle for 64-byte rows (32 bf16), 16B chunks ch=0..3 (measured 0-conflict)
static __device__ __forceinline__ int swz64(int r, int ch){
  return r*64 + (((ch ^ (r>>1)) & 3) << 4);
}
// swizzle for 128-byte rows (64 bf16), 16B chunks ch=0..7
static __device__ __forceinline__ int swz128(int r, int ch){
  return r*128 + (((ch ^ r) & 7) << 4);
}

// async 16B global->LDS; lds base must be wave-uniform, HW adds lane*16
static __device__ __forceinline__ void gl16(const short* g, short* l){
  __builtin_amdgcn_global_load_lds(
      (const __attribute__((address_space(1))) void*)g,
      (__attribute__((address_space(3))) void*)l, 16, 0, 0);
}

// ---------------- ALL weight transposes in one launch ----------------
// out[c][r] = in[r][c] per segment; 64x64 tiles, 256 thr.
// Segments (flat block id): [0,768) Wqkv 16x48 tiles; [768,1024) Wproj 16x16;
// [1024,9216) W1 8x(16x64); [9216,17408) W2 8x(64x16).
__global__ void k_transpose_all(const float* __restrict__ Wqkv, const float* __restrict__ Wproj,
                                const float* __restrict__ W1, const float* __restrict__ W2,
                                short* __restrict__ WtQ, short* __restrict__ WtP,
                                short* __restrict__ Wt1, short* __restrict__ Wt2){
  const int id = blockIdx.x;
  const float* src; short* dst; int R, Cc, bx, by;
  if (id < 768){                       // W_qkv [1024][3072]
    src = Wqkv; dst = WtQ; R = 1024; Cc = 3072;
    bx = id % 48; by = id / 48;
  } else if (id < 1024){               // W_proj [1024][1024]
    const int t = id - 768;
    src = Wproj; dst = WtP; R = 1024; Cc = 1024;
    bx = t % 16; by = t / 16;
  } else if (id < 9216){               // W1 [8][1024][4096]
    const int t = id - 1024, z = t >> 10, tt = t & 1023;
    src = W1 + (long long)z*1024*4096; dst = Wt1 + (long long)z*1024*4096;
    R = 1024; Cc = 4096;
    bx = tt % 64; by = tt / 64;
  } else {                             // W2 [8][4096][1024]
    const int t = id - 9216, z = t >> 10, tt = t & 1023;
    src = W2 + (long long)z*4096*1024; dst = Wt2 + (long long)z*4096*1024;
    R = 4096; Cc = 1024;
    bx = tt % 16; by = tt / 16;
  }
  __shared__ float tile[64][65];
  const int r0 = by*64, c0 = bx*64;
  const int t = threadIdx.x;
  #pragma unroll
  for (int it=0; it<4; ++it){
    const int item = t + it*256;
    const int r = item>>4, c4 = item&15;
    const float4 v = *(const float4*)(src + (long long)(r0+r)*Cc + c0 + c4*4);
    tile[r][c4*4+0]=v.x; tile[r][c4*4+1]=v.y; tile[r][c4*4+2]=v.z; tile[r][c4*4+3]=v.w;
  }
  __syncthreads();
  #pragma unroll
  for (int it=0; it<2; ++it){
    const int item = t + it*256;
    const int rr8 = item & 7, cc = item >> 3;
    bf16x8 o;
    #pragma unroll
    for (int i=0;i<8;i++) o[i] = f2bf(tile[rr8*8+i][cc]);
    *(bf16x8*)(dst + (long long)(c0+cc)*R + r0 + rr8*8) = o;
  }
}

// ---------------- LayerNorm 1 -> bf16 (+ pipeline-state init, replaces memsets) -----
__global__ void k_ln1(const float* __restrict__ x, const float* __restrict__ g,
                      const float* __restrict__ b, short* __restrict__ out,
                      int* __restrict__ counts, int* __restrict__ curs,
                      int* __restrict__ zrowi, int* __restrict__ rowmap){
  const int row = blockIdx.x;
  const int t = threadIdx.x;
  // distributed init (all consumers launch after this kernel)
  const int gid = row*256 + t;
  if (gid < 2048) zrowi[gid] = 0;
  if (gid < MAXROWS) rowmap[gid] = -1;
  if (gid < 8){ counts[gid] = 0; curs[gid] = 0; }

  const float4 v = ((const float4*)(x + (long long)row*CDIM))[t];
  float s  = v.x+v.y+v.z+v.w;
  float s2 = v.x*v.x+v.y*v.y+v.z*v.z+v.w*v.w;
  #pragma unroll
  for (int mm=1; mm<64; mm<<=1){ s += __shfl_xor(s,mm); s2 += __shfl_xor(s2,mm); }
  __shared__ float ps[4], ps2[4];
  const int w = t>>6, l = t&63;
  if (l==0){ ps[w]=s; ps2[w]=s2; }
  __syncthreads();
  s  = ps[0]+ps[1]+ps[2]+ps[3];
  s2 = ps2[0]+ps2[1]+ps2[2]+ps2[3];
  const float mu = s*(1.f/CDIM);
  const float rstd = rsqrtf(s2*(1.f/CDIM) - mu*mu + 1e-5f);
  const float4 gg = ((const float4*)g)[t];
  const float4 bb = ((const float4*)b)[t];
  s16x4 o;
  o[0]=f2bf((v.x-mu)*rstd*gg.x+bb.x); o[1]=f2bf((v.y-mu)*rstd*gg.y+bb.y);
  o[2]=f2bf((v.z-mu)*rstd*gg.z+bb.z); o[3]=f2bf((v.w-mu)*rstd*gg.w+bb.w);
  *(s16x4*)(out + (long long)row*CDIM + t*4) = o;
}

// ---------------- LayerNorm 2 + router (fp32 logits) ----------------
__global__ void k_ln2_router(const float* __restrict__ x1, const float* __restrict__ g,
                             const float* __restrict__ b, const float* __restrict__ Wr,
                             short* __restrict__ h2, int* __restrict__ tidx,
                             float* __restrict__ tw, int* __restrict__ counts){
  const int row = blockIdx.x;
  const int t = threadIdx.x;
  const float4 v = ((const float4*)(x1 + (long long)row*CDIM))[t];
  float s  = v.x+v.y+v.z+v.w;
  float s2 = v.x*v.x+v.y*v.y+v.z*v.z+v.w*v.w;
  #pragma unroll
  for (int mm=1; mm<64; mm<<=1){ s += __shfl_xor(s,mm); s2 += __shfl_xor(s2,mm); }
  __shared__ float ps[4], ps2[4];
  const int w = t>>6, l = t&63;
  if (l==0){ ps[w]=s; ps2[w]=s2; }
  __syncthreads();
  s  = ps[0]+ps[1]+ps[2]+ps[3];
  s2 = ps2[0]+ps2[1]+ps2[2]+ps2[3];
  const float mu = s*(1.f/CDIM);
  const float rstd = rsqrtf(s2*(1.f/CDIM) - mu*mu + 1e-5f);
  const float4 gg = ((const float4*)g)[t];
  const float4 bb = ((const float4*)b)[t];
  const float y0=(v.x-mu)*rstd*gg.x+bb.x, y1=(v.y-mu)*rstd*gg.y+bb.y;
  const float y2=(v.z-mu)*rstd*gg.z+bb.z, y3=(v.w-mu)*rstd*gg.w+bb.w;
  s16x4 o; o[0]=f2bf(y0); o[1]=f2bf(y1); o[2]=f2bf(y2); o[3]=f2bf(y3);
  *(s16x4*)(h2 + (long long)row*CDIM + t*4) = o;

  float acc[8];
  const float* wr0 = Wr + (long long)(t*4)*NEXP;
  #pragma unroll
  for (int e=0;e<8;e++) acc[e] = y0*wr0[e] + y1*wr0[8+e] + y2*wr0[16+e] + y3*wr0[24+e];
  #pragma unroll
  for (int mm=1; mm<64; mm<<=1){
    #pragma unroll
    for (int e=0;e<8;e++) acc[e] += __shfl_xor(acc[e], mm);
  }
  __shared__ float pl[4][8];
  if (l==0){
    #pragma unroll
    for (int e=0;e<8;e++) pl[w][e]=acc[e];
  }
  __syncthreads();
  if (t==0){
    float lg[8];
    #pragma unroll
    for (int e=0;e<8;e++) lg[e] = pl[0][e]+pl[1][e]+pl[2][e]+pl[3][e];
    float mx = lg[0];
    #pragma unroll
    for (int e=1;e<8;e++) mx = fmaxf(mx, lg[e]);
    float pr[8]; float sum = 0.f;
    #pragma unroll
    for (int e=0;e<8;e++){ pr[e]=expf(lg[e]-mx); sum += pr[e]; }
    int i0 = 0;
    #pragma unroll
    for (int e=1;e<8;e++) if (pr[e] > pr[i0]) i0 = e;
    int i1 = (i0==0) ? 1 : 0;
    #pragma unroll
    for (int e=0;e<8;e++) if (e!=i0 && pr[e] > pr[i1]) i1 = e;
    const float p0 = pr[i0]/sum, p1 = pr[i1]/sum;
    const float dn = p0 + p1 + 1e-9f;
    tidx[row*2]=i0; tidx[row*2+1]=i1;
    tw[row*2]=p0/dn; tw[row*2+1]=p1/dn;
    atomicAdd(&counts[i0],1); atomicAdd(&counts[i1],1);
  }
}

// ---------------- scatter + inline route-setup ----------------
__global__ void k_scatter(const int* __restrict__ tidx, const float* __restrict__ tw,
                          const int* __restrict__ counts, int* __restrict__ curs0,
                          int* __restrict__ offs, float* __restrict__ util,
                          int* __restrict__ rowmap, float* __restrict__ roww,
                          int* __restrict__ posmap){
  __shared__ int soff[9];
  if (threadIdx.x == 0){
    int o = 0;
    for (int e=0;e<8;e++){
      soff[e] = o;
      o += (counts[e] + 127) & ~127;
    }
    soff[8] = o;
    if (blockIdx.x == 0){
      for (int e=0;e<9;e++) offs[e] = soff[e];
      for (int e=0;e<8;e++) util[e] = (float)counts[e] / 8192.0f;
    }
  }
  __syncthreads();
  const int i = blockIdx.x*blockDim.x + threadIdx.x;
  if (i >= 2*NTOK) return;
  const int e = tidx[i];
  const int pos = soff[e] + atomicAdd(&curs0[e], 1);
  rowmap[pos] = i >> 1;
  roww[pos]   = tw[i];
  posmap[i]   = pos;
}

// ---------------- GEMM 128x128 (proven): 512 thr, 2-buf, vmcnt(0), mtile-major -------
// EPI 0: +bias -> bf16 (QKV) | EPI 1: +bias +resid -> f32 (proj)
// EPI 2: gather + GELU(tanh) -> bf16 (MoE up) | EPI 3: per-expert bias -> bf16 (MoE down)
template<int EPI>
__launch_bounds__(512, 4)
__global__ void k_gemm(const short* __restrict__ A, const short* __restrict__ Bt,
                       const float* __restrict__ bias, const float* __restrict__ resid,
                       void* __restrict__ Cout, int N, int K,
                       const int* __restrict__ rowmap, const int* __restrict__ offs,
                       long long expStrideB, const short* __restrict__ zrow){
  // bijective XCD swizzle (m204)
  int wg = blockIdx.x;
  const int nwg = gridDim.x;
  {
    const int q = nwg >> 3, r8 = nwg & 7;
    const int xcd = wg & 7, pos = wg >> 3;
    wg = (xcd < r8 ? xcd*(q+1) : r8*(q+1) + (xcd - r8)*q) + pos;
  }
  const int gridN = N >> 7;
  const int mtile = wg / gridN, ntile = wg % gridN;   // mtile-major
  const int mbase = mtile*128;
  const int nbase = ntile*128;
  int e = 0;
  if constexpr (EPI >= 2){
    if (mbase >= offs[8]) return;
    while (e < 7 && mbase >= offs[e+1]) e++;
    Bt += (long long)e * expStrideB;
  }
  __shared__ short Asm[2][4096];
  __shared__ short Bsm[2][4096];
  const int tid = threadIdx.x;
  const int w = tid >> 6, l = tid & 63;
  const int wr = w >> 1, wc = w & 1;       // 4M x 2N wave grid
  const int l15 = l & 15, l4 = l >> 4;

  const short* aSrc; const short* bSrc;
  {
    const int r = tid >> 2, ch = tid & 3;
    const int sch = (ch ^ (r >> 1)) & 3;   // source chunk (involution of swz64)
    if constexpr (EPI == 2){
      const int grow = rowmap[mbase + r];
      aSrc = (grow >= 0) ? (A + (long long)grow*K + sch*8) : (zrow + sch*8);
    } else {
      aSrc = A + (long long)(mbase + r)*K + sch*8;
    }
    bSrc = Bt + (long long)(nbase + r)*K + sch*8;
  }
  const int dOff = w*512;                  // wave-uniform shorts offset

  f32x4 acc[2][4];
  const f32x4 z4 = {0.f,0.f,0.f,0.f};
  #pragma unroll
  for (int i=0;i<2;i++){
    #pragma unroll
    for (int jn=0;jn<4;jn++) acc[i][jn] = z4;
  }

  auto stage = [&](int buf, int kt){
    gl16(aSrc + kt, &Asm[buf][dOff]);
    gl16(bSrc + kt, &Bsm[buf][dOff]);
  };
  auto compute = [&](int buf){
    bf16x8 af[2], bfr[4];
    #pragma unroll
    for (int i=0;i<2;i++)
      af[i]  = *(const bf16x8*)((char*)Asm[buf] + swz64(wr*32 + i*16 + l15, l4));
    #pragma unroll
    for (int jn=0;jn<4;jn++)
      bfr[jn] = *(const bf16x8*)((char*)Bsm[buf] + swz64(wc*64 + jn*16 + l15, l4));
    #pragma unroll
    for (int i=0;i<2;i++){
      #pragma unroll
      for (int jn=0;jn<4;jn++)
        acc[i][jn] = __builtin_amdgcn_mfma_f32_16x16x32_bf16(af[i], bfr[jn], acc[i][jn], 0,0,0);
    }
  };

  stage(0, 0);
  asm volatile("s_waitcnt vmcnt(0)" ::: "memory");
  __builtin_amdgcn_s_barrier();

  int cur = 0;
  for (int kt = 32; kt < K; kt += 32){
    stage(cur ^ 1, kt);
    compute(cur);
    asm volatile("s_waitcnt vmcnt(0)" ::: "memory");
    __builtin_amdgcn_s_barrier();
    cur ^= 1;
  }
  compute(cur);

  #pragma unroll
  for (int i=0;i<2;i++){
    const int row0 = mbase + wr*32 + i*16 + l4*4;
    #pragma unroll
    for (int jn=0;jn<4;jn++){
      const int col = nbase + wc*64 + jn*16 + l15;
      const float bi = bias[(EPI>=2 ? e*N : 0) + col];
      #pragma unroll
      for (int j=0;j<4;j++){
        const long long idx = (long long)(row0 + j)*N + col;
        float v = acc[i][jn][j] + bi;
        if constexpr (EPI == 0){
          ((short*)Cout)[idx] = f2bf(v);
        } else if constexpr (EPI == 1){
          ((float*)Cout)[idx] = v + resid[idx];
        } else if constexpr (EPI == 2){
          ((short*)Cout)[idx] = f2bf(gelu_t(v));
        } else {
          ((short*)Cout)[idx] = f2bf(v);
        }
      }
    }
  }
}

// ---------------- flash attention (causal), 128 q rows / block, KVBLK=128 ------------
__launch_bounds__(512)
__global__ void k_attn(const short* __restrict__ qkv, short* __restrict__ y){
  const int qp = blockIdx.x;       // q pair (128 rows)
  const int bh = blockIdx.y;
  const int bb = bh >> 4;
  const int h  = bh & 15;
  const int tid = threadIdx.x;
  const int w = tid >> 6, l = tid & 63;
  const int half = w >> 2, wq = w & 3;
  const int l15 = l & 15, l4 = l >> 4;

  __shared__ short Ksm[128*64];    // 128 kv rows x 64 d (swz128 rows)
  __shared__ short Vtsm[64*128];   // 64 d rows x 128 kv cols (256B rows, XOR-chunk swz)
  __shared__ short Psm[8*16*64];

  const long long rs = 3*CDIM;
  const int qrow0 = bb*1024 + qp*128;
  const int myQt = (qp << 1) + half;      // my 64-row q-tile index

  bf16x8 aq[2];
  {
    const int qr = qrow0 + half*64 + wq*16 + l15;
    const short* qp2 = qkv + (long long)qr*rs + h*HDIM;
    aq[0] = *(const bf16x8*)(qp2 + l4*8);
    aq[1] = *(const bf16x8*)(qp2 + 32 + l4*8);
  }

  const f32x4 z4 = {0.f,0.f,0.f,0.f};
  f32x4 O[4];
  #pragma unroll
  for (int cf=0;cf<4;cf++) O[cf] = z4;
  float mrow[4], lrow[4];
  #pragma unroll
  for (int j=0;j<4;j++){ mrow[j] = -1e30f; lrow[j] = 0.f; }

  for (int it = 0; it <= qp; ++it){
    const int kvrow0 = bb*1024 + it*128;
    #pragma unroll
    for (int pz=0; pz<2; ++pz){
      const int rr = (tid >> 3) + pz*64;   // kv row 0..127
      const int c = tid & 7;
      const short* kp = qkv + (long long)(kvrow0 + rr)*rs + CDIM + h*HDIM + c*8;
      *(bf16x8*)((char*)Ksm + swz128(rr, c)) = *(const bf16x8*)kp;
      const short* vp = qkv + (long long)(kvrow0 + rr)*rs + 2*CDIM + h*HDIM + c*8;
      bf16x8 vv = *(const bf16x8*)vp;
      #pragma unroll
      for (int i=0;i<8;i++){
        const int d = c*8 + i;
        *(short*)((char*)Vtsm + d*256 + ((((rr>>3) ^ (d&7)) & 15)<<4) + ((2*rr)&15)) = vv[i];
      }
    }
    __syncthreads();

    #pragma unroll
    for (int ks=0; ks<2; ++ks){
      const int kvb = it*2 + ks;
      if (kvb <= myQt){
        f32x4 S[4];
        #pragma unroll
        for (int cf=0;cf<4;cf++) S[cf] = z4;
        #pragma unroll
        for (int cf=0;cf<4;cf++){
          #pragma unroll
          for (int kf=0;kf<2;kf++){
            bf16x8 bk = *(const bf16x8*)((char*)Ksm + swz128(ks*64 + cf*16 + l15, kf*4 + l4));
            S[cf] = __builtin_amdgcn_mfma_f32_16x16x32_bf16(aq[kf], bk, S[cf], 0,0,0);
          }
        }

        const bool diag = (kvb == myQt);
        #pragma unroll
        for (int cf=0;cf<4;cf++){
          #pragma unroll
          for (int j=0;j<4;j++){
            float s = S[cf][j] * 0.125f;
            if (diag && (cf*16 + l15 > wq*16 + l4*4 + j)) s = -1e30f;
            S[cf][j] = s;
          }
        }

        float alpha[4];
        #pragma unroll
        for (int j=0;j<4;j++){
          float mx = fmaxf(fmaxf(S[0][j],S[1][j]), fmaxf(S[2][j],S[3][j]));
          #pragma unroll
          for (int mm=1; mm<16; mm<<=1) mx = fmaxf(mx, __shfl_xor(mx, mm));
          const float mnew = fmaxf(mrow[j], mx);
          const float al = expf(mrow[j] - mnew);
          float psum = 0.f;
          #pragma unroll
          for (int cf=0;cf<4;cf++){ float pp = expf(S[cf][j]-mnew); S[cf][j]=pp; psum += pp; }
          #pragma unroll
          for (int mm=1; mm<16; mm<<=1) psum += __shfl_xor(psum, mm);
          lrow[j] = lrow[j]*al + psum;
          mrow[j] = mnew; alpha[j] = al;
        }
        #pragma unroll
        for (int cf=0;cf<4;cf++){
          #pragma unroll
          for (int j=0;j<4;j++) O[cf][j] *= alpha[j];
        }

        char* pw = (char*)Psm + w*2048;
        #pragma unroll
        for (int cf=0;cf<4;cf++){
          #pragma unroll
          for (int j=0;j<4;j++){
            const int r = l4*4 + j;
            const int cb = (cf*16 + l15)*2;
            *(short*)(pw + r*128 + ((((cb>>4) ^ r) & 7)<<4) + (cb & 15)) = f2bf(S[cf][j]);
          }
        }
        bf16x8 pa[2];
        pa[0] = *(const bf16x8*)(pw + swz128(l15, l4));
        pa[1] = *(const bf16x8*)(pw + swz128(l15, 4 + l4));
        #pragma unroll
        for (int cf=0;cf<4;cf++){
          const int d = cf*16 + l15;
          #pragma unroll
          for (int kf=0;kf<2;kf++){
            const int ch = ks*8 + kf*4 + l4;
            bf16x8 bv = *(const bf16x8*)((char*)Vtsm + d*256 + (((ch ^ (d&7)) & 15)<<4));
            O[cf] = __builtin_amdgcn_mfma_f32_16x16x32_bf16(pa[kf], bv, O[cf], 0,0,0);
          }
        }
      }
    }
    __syncthreads();
  }

  const int yr0 = qrow0 + half*64 + wq*16;
  #pragma unroll
  for (int cf=0;cf<4;cf++){
    #pragma unroll
    for (int j=0;j<4;j++){
      const int r = l4*4 + j;
      y[(long long)(yr0 + r)*CDIM + h*HDIM + cf*16 + l15] = f2bf(O[cf][j] / lrow[j]);
    }
  }
}

// ---------------- final combine: out = x1 + w0*eo[p0] + w1*eo[p1] (eo bf16) ---------
__global__ void k_combine(const float* __restrict__ x1, const short* __restrict__ eo,
                          const int* __restrict__ posmap, const float* __restrict__ roww,
                          float* __restrict__ out){
  const int row = blockIdx.x;
  const int t = threadIdx.x;
  const int p0 = posmap[row*2], p1 = posmap[row*2+1];
  const float w0 = roww[p0], w1 = roww[p1];
  const float4 a  = ((const float4*)(x1 + (long long)row*CDIM))[t];
  const s16x4 e0 = *(const s16x4*)(eo + (long long)p0*CDIM + t*4);
  const s16x4 e1 = *(const s16x4*)(eo + (long long)p1*CDIM + t*4);
  float4 r;
  r.x = a.x + w0*bf2f(e0[0]) + w1*bf2f(e1[0]);
  r.y = a.y + w0*bf2f(e0[1]) + w1*bf2f(e1[1]);
  r.z = a.z + w0*bf2f(e0[2]) + w1*bf2f(e1[2]);
  r.w = a.w + w0*bf2f(e0[3]) + w1*bf2f(e1[3]);
  ((float4*)(out + (long long)row*CDIM))[t] = r;
}

extern "C" void kernel_launch(void* const* d_in, const int* in_sizes, int n_in,
                              void* d_out, int out_size, void* d_ws, size_t ws_size,
                              hipStream_t stream){
  const float* x     = (const float*)d_in[0];
  const float* ln1_g = (const float*)d_in[1];
  const float* ln1_b = (const float*)d_in[2];
  const float* W_qkv = (const float*)d_in[3];
  const float* b_qkv = (const float*)d_in[4];
  const float* W_proj= (const float*)d_in[5];
  const float* b_proj= (const float*)d_in[6];
  const float* ln2_g = (const float*)d_in[7];
  const float* ln2_b = (const float*)d_in[8];
  const float* W_r   = (const float*)d_in[9];
  const float* W1    = (const float*)d_in[10];
  const float* b1    = (const float*)d_in[11];
  const float* W2    = (const float*)d_in[12];
  const float* b2    = (const float*)d_in[13];
  float* out = (float*)d_out;
  float* util = out + (long long)NTOK*CDIM;

  char* p = (char*)d_ws;
  auto alloc = [&](size_t bytes)->char*{
    char* r = p; p += (bytes + 255) & ~(size_t)255; return r;
  };
  // persistent region
  short* Wt1   = (short*)alloc((size_t)NEXP*HIDD*CDIM*2);
  short* Wt2   = (short*)alloc((size_t)NEXP*CDIM*HIDD*2);
  float* x1    = (float*)alloc((size_t)NTOK*CDIM*4);
  short* h2    = (short*)alloc((size_t)NTOK*CDIM*2);
  short* hid   = (short*)alloc((size_t)MAXROWS*HIDD*2);
  int*   tidx  = (int*)alloc(2*NTOK*4);
  float* tw    = (float*)alloc(2*NTOK*4);
  int*   counts= (int*)alloc(256);
  int*   offs  = (int*)alloc(256);
  int*   curs  = (int*)alloc(256);
  int*   rowmap= (int*)alloc(MAXROWS*4);
  float* roww  = (float*)alloc(MAXROWS*4);
  int*   posmap= (int*)alloc(2*NTOK*4);
  short* zrow  = (short*)alloc(8192);
  // transient region (dead after proj GEMM) -- eo aliases it afterwards
  char* transStart = p;
  short* WtQ = (short*)alloc((size_t)3*CDIM*CDIM*2);
  short* WtP = (short*)alloc((size_t)CDIM*CDIM*2);
  short* h   = (short*)alloc((size_t)NTOK*CDIM*2);
  short* qkv = (short*)alloc((size_t)NTOK*3*CDIM*2);
  short* y   = (short*)alloc((size_t)NTOK*CDIM*2);
  short* eo  = (short*)transStart;  // MAXROWS*CDIM*2 = 18.9MB <= transient

  k_ln1<<<NTOK, 256, 0, stream>>>(x, ln1_g, ln1_b, h, counts, curs, (int*)zrow, rowmap);

  k_transpose_all<<<17408, 256, 0, stream>>>(W_qkv, W_proj, W1, W2, WtQ, WtP, Wt1, Wt2);

  k_gemm<0><<<dim3((NTOK/128)*(3*CDIM/128)), 512, 0, stream>>>(
      h, WtQ, b_qkv, nullptr, qkv, 3*CDIM, CDIM, nullptr, nullptr, 0, nullptr);

  k_attn<<<dim3(1024/128, 4*NHEAD), 512, 0, stream>>>(qkv, y);

  k_gemm<1><<<dim3((NTOK/128)*(CDIM/128)), 512, 0, stream>>>(
      y, WtP, b_proj, x, x1, CDIM, CDIM, nullptr, nullptr, 0, nullptr);

  k_ln2_router<<<NTOK, 256, 0, stream>>>(x1, ln2_g, ln2_b, W_r, h2, tidx, tw, counts);
  k_scatter<<<(2*NTOK)/256, 256, 0, stream>>>(tidx, tw, counts, curs, offs, util,
                                              rowmap, roww, posmap);

  k_gemm<2><<<dim3((MAXROWS/128)*(HIDD/128)), 512, 0, stream>>>(
      h2, Wt1, b1, nullptr, hid, HIDD, CDIM, rowmap, offs, (long long)HIDD*CDIM, zrow);
  k_gemm<3><<<dim3((MAXROWS/128)*(CDIM/128)), 512, 0, stream>>>(
      hid, Wt2, b2, nullptr, eo, CDIM, HIDD, nullptr, offs, (long long)CDIM*HIDD, zrow);

  k_combine<<<NTOK, 256, 0, stream>>>(x1, eo, posmap, roww, out);
}